// Round 7
// baseline (1225.977 us; speedup 1.0000x reference)
//
#include <hip/hip_runtime.h>
#include <hip/hip_bf16.h>
#include <math.h>

// ---------------------------------------------------------------------------
// Morpher forward. All large GEMMs bf16 MFMA; encoder low-rank folded;
// flash attention Q-in-registers.
// R8: flash LDS XOR-swizzle. R9: gemm_bf16_256 deep pipeline (counted vmcnt).
// R10: inline-asm ds_read_b128 (compiler LDS-DMA alias tracking re-inserted
//      vmcnt(0) -> depth-0; asm reads are opaque).
// R11: flash dbuf + counted vmcnt + LPT work queue.
// R12: flash BQ=128 8-wave blocks. R13: launch_bounds (512,2) fixes the
//      (512,4)-forced VGPR=64 scratch spill (2x slowdown).
// R14: decoder down-projection moved off the fp32 splitk path (MfmaUtil=0,
//      LDS-throughput-bound, 95us) onto gemm_bf16_256: decoder LN emits bf16,
//      dec_down bf16 padded to 128 rows, direct write (no atomics/memset).
//      Epilogue col<N guard added (no-op elsewhere).
// Shapes: B=8 T=1024 (BT=8192), N=4, K=3, S=7, DH=128, D=896, ND=3584,
// IO=1024, RANK=64, HIDDEN=3584.
// ---------------------------------------------------------------------------

#define BT   8192
#define DH   128
#define DD   896
#define ND   3584
#define IO   1024
#define RK   64
#define HID  3584

typedef __attribute__((ext_vector_type(8))) short short8;
typedef __attribute__((ext_vector_type(4))) float f32x4;
typedef __hip_bfloat16 bf16;

// inline-asm LDS read: opaque to SIInsertWaitcnts' LDS-DMA tracking.
#define DS_READ_B128(dst, p)                                                  \
    asm volatile("ds_read_b128 %0, %1"                                        \
                 : "=v"(dst)                                                  \
                 : "v"((const __attribute__((address_space(3))) bf16*)(p)))

// Fast gelu: exact-form 0.5x(1+erf(x/sqrt2)) with A&S 7.1.26 erf
__device__ __forceinline__ float gelu_f(float v)
{
    float u = v * 0.70710678118654752f;
    float a = fabsf(u);
    float t = __builtin_amdgcn_rcpf(1.0f + 0.3275911f * a);
    float p = t * (0.254829592f + t * (-0.284496736f + t * (1.421413741f +
              t * (-1.453152027f + t * 1.061405429f))));
    float er = 1.0f - p * __expf(-u * u);
    er = copysignf(er, u);
    return 0.5f * v * (1.0f + er);
}

// ---------------------------------------------------------------------------
// fp32 tiled GEMM (decoder up-projection only). C = A @ B^T, B (N x Kd) rm.
// ---------------------------------------------------------------------------
template<int BM, int BN, int BK, int TM, int TN>
__global__ __launch_bounds__(256) void gemm_kernel(const float* __restrict__ A,
                                                   const float* __restrict__ B,
                                                   float* __restrict__ C,
                                                   int N, int Kd)
{
    constexpr int THREADS = (BM / TM) * (BN / TN);
    constexpr int LDA = BM + 4;
    constexpr int LDB = BN + 4;
    __shared__ float As[BK][LDA];
    __shared__ float Bs[BK][LDB];

    const int tid = threadIdx.x;
    constexpr int NX = BN / TN;
    const int tx = tid % NX;
    const int ty = tid / NX;
    const int row0 = blockIdx.y * BM;
    const int col0 = blockIdx.x * BN;

    float acc[TM][TN];
#pragma unroll
    for (int i = 0; i < TM; ++i)
#pragma unroll
        for (int j = 0; j < TN; ++j) acc[i][j] = 0.f;

    for (int k0 = 0; k0 < Kd; k0 += BK) {
        constexpr int AF4 = BM * BK / 4;
        for (int f = tid; f < AF4; f += THREADS) {
            int r  = f / (BK / 4);
            int c4 = (f % (BK / 4)) * 4;
            float4 v = *(const float4*)(A + (size_t)(row0 + r) * Kd + k0 + c4);
            As[c4 + 0][r] = v.x; As[c4 + 1][r] = v.y;
            As[c4 + 2][r] = v.z; As[c4 + 3][r] = v.w;
        }
        constexpr int BF4 = BN * BK / 4;
        for (int f = tid; f < BF4; f += THREADS) {
            int r  = f / (BK / 4);
            int c4 = (f % (BK / 4)) * 4;
            float4 v = *(const float4*)(B + (size_t)(col0 + r) * Kd + k0 + c4);
            Bs[c4 + 0][r] = v.x; Bs[c4 + 1][r] = v.y;
            Bs[c4 + 2][r] = v.z; Bs[c4 + 3][r] = v.w;
        }
        __syncthreads();

#pragma unroll
        for (int kk = 0; kk < BK; ++kk) {
            float a[TM], b[TN];
#pragma unroll
            for (int i = 0; i < TM; i += 4)
                *(float4*)&a[i] = *(const float4*)&As[kk][ty * TM + i];
#pragma unroll
            for (int j = 0; j < TN; j += 4)
                *(float4*)&b[j] = *(const float4*)&Bs[kk][tx * TN + j];
#pragma unroll
            for (int i = 0; i < TM; ++i)
#pragma unroll
                for (int j = 0; j < TN; ++j)
                    acc[i][j] = fmaf(a[i], b[j], acc[i][j]);
        }
        __syncthreads();
    }

    const int crow = row0 + ty * TM;
    const int ccol = col0 + tx * TN;
#pragma unroll
    for (int i = 0; i < TM; ++i) {
        float* cp = C + (size_t)(crow + i) * N + ccol;
#pragma unroll
        for (int j = 0; j < TN; ++j) cp[j] = acc[i][j];
    }
}

// ---------------------------------------------------------------------------
// R9/R10: bf16 MFMA GEMM, 256xBN tile, 8 waves (512 thr), C = A @ B^T.
// LDS ring of 4 K-half slots, depth-3 prefetch via global_load_lds w16,
// counted vmcnt, inline-asm ds_read_b128 fragments, setprio MFMA cluster,
// XCD-chunked block swizzle. 2 barriers per K-half.
// R14: epilogue stores guarded by col < N (lets BN=128 compute a padded
// 64-col output for the decoder down-projection).
//  EPI 0: Cf = acc ; EPI 1: Cb = bf16(gelu(acc+bias)) ; EPI 2: Cf += acc+bias
// ---------------------------------------------------------------------------
template<int BN, int EPI>
__global__ __launch_bounds__(512, 2) void gemm_bf16_256(
    const bf16* __restrict__ A,
    const bf16* __restrict__ B,
    float* __restrict__ Cf,
    bf16* __restrict__ Cb,
    int N, int Kd,
    const float* __restrict__ bias)
{
    constexpr int NR    = BN / 64;        // n-frags per wave (4 or 2)
    constexpr int WTN   = 16 * NR;        // wave tile cols
    constexpr int ASLOT = 256 * 32;       // elements per A K-half slot
    constexpr int BSLOT = BN * 32;
    __shared__ bf16 As[4 * ASLOT];
    __shared__ bf16 Bs[4 * BSLOT];

    const int tid  = threadIdx.x;
    const int wave = tid >> 6;
    const int lane = tid & 63;
    const int wm = wave >> 2, wn = wave & 3;
    const int lr = lane & 15, lq = lane >> 4;

    // T1: XCD-chunked block swizzle (nwg % 8 == 0 at every call site)
    const int gx  = gridDim.x;
    int fid = blockIdx.y * gx + blockIdx.x;
    const int cpx = (gx * gridDim.y) >> 3;
    fid = (fid & 7) * cpx + (fid >> 3);
    const int row0 = (fid / gx) * 256;
    const int col0 = (fid % gx) * BN;

    // staging per-lane constants (16 rows x 64 B per wave-issue)
    const int sr  = lane >> 2;                               // 0..15
    const int scs = (((lane & 3) ^ ((lane >> 3) & 3)) << 3); // swizzled src col
    const bf16* Ag = A + (size_t)(row0 + sr) * Kd + scs;
    const bf16* Bg = B + (size_t)(col0 + sr) * Kd + scs;

    // read-side per-lane swizzle (row&15 == lr on every read path)
    const int scox = (lq * 8) ^ (((lr >> 1) & 3) << 3);

    f32x4 acc[8][NR];
#pragma unroll
    for (int i = 0; i < 8; ++i)
#pragma unroll
        for (int j = 0; j < NR; ++j) acc[i][j] = (f32x4){0.f, 0.f, 0.f, 0.f};

    const int NH = Kd >> 5;   // number of K-halves (>= 28 at all call sites)

    auto stage = [&](int h) {
        const int slot = h & 3;
#pragma unroll
        for (int i = 0; i < 2; ++i) {
            const int rg = (i * 8 + wave) * 16;
            __builtin_amdgcn_global_load_lds(
                (const __attribute__((address_space(1))) unsigned int*)
                    (Ag + (size_t)rg * Kd + h * 32),
                (__attribute__((address_space(3))) unsigned int*)
                    (As + slot * ASLOT + rg * 32),
                16, 0, 0);
        }
#pragma unroll
        for (int i = 0; i < BN / 128; ++i) {
            const int rg = (i * 8 + wave) * 16;
            __builtin_amdgcn_global_load_lds(
                (const __attribute__((address_space(1))) unsigned int*)
                    (Bg + (size_t)rg * Kd + h * 32),
                (__attribute__((address_space(3))) unsigned int*)
                    (Bs + slot * BSLOT + rg * 32),
                16, 0, 0);
        }
    };

    // prologue: 3 K-halves in flight
    stage(0); stage(1); stage(2);

    for (int h = 0; h < NH; ++h) {
        if (h + 3 < NH) stage(h + 3);

        // counted vmcnt: wait only for stage(h)'s loads (oldest LPH).
        const int ahead = NH - 1 - h;
        if constexpr (BN == 256) {   // LPH = 4
            if (ahead >= 3)      asm volatile("s_waitcnt vmcnt(12)" ::: "memory");
            else if (ahead == 2) asm volatile("s_waitcnt vmcnt(8)"  ::: "memory");
            else if (ahead == 1) asm volatile("s_waitcnt vmcnt(4)"  ::: "memory");
            else                 asm volatile("s_waitcnt vmcnt(0)"  ::: "memory");
        } else {                     // LPH = 3
            if (ahead >= 3)      asm volatile("s_waitcnt vmcnt(9)"  ::: "memory");
            else if (ahead == 2) asm volatile("s_waitcnt vmcnt(6)"  ::: "memory");
            else if (ahead == 1) asm volatile("s_waitcnt vmcnt(3)"  ::: "memory");
            else                 asm volatile("s_waitcnt vmcnt(0)"  ::: "memory");
        }
        __builtin_amdgcn_s_barrier();            // all waves' half-h data in LDS

        const bf16* Ab = As + (h & 3) * ASLOT;
        const bf16* Bb = Bs + (h & 3) * BSLOT;

        short8 bfr[NR], afr[8];
#pragma unroll
        for (int nt = 0; nt < NR; ++nt)
            DS_READ_B128(bfr[nt], Bb + (wn * WTN + nt * 16 + lr) * 32 + scox);
#pragma unroll
        for (int mt = 0; mt < 8; ++mt)
            DS_READ_B128(afr[mt], Ab + (wm * 128 + mt * 16 + lr) * 32 + scox);

        asm volatile("s_waitcnt lgkmcnt(0)" ::: "memory");
        __builtin_amdgcn_sched_barrier(0);       // rule #18: pin MFMAs below wait

        __builtin_amdgcn_s_setprio(1);
#pragma unroll
        for (int mt = 0; mt < 8; ++mt)
#pragma unroll
            for (int nt = 0; nt < NR; ++nt)
                acc[mt][nt] = __builtin_amdgcn_mfma_f32_16x16x32_bf16(
                    afr[mt], bfr[nt], acc[mt][nt], 0, 0, 0);
        __builtin_amdgcn_s_setprio(0);

        __builtin_amdgcn_s_barrier();            // all reads of slot h&3 done
    }

#pragma unroll
    for (int mt = 0; mt < 8; ++mt) {
#pragma unroll
        for (int nt = 0; nt < NR; ++nt) {
            const int col = col0 + wn * WTN + nt * 16 + lr;
            const bool cok = (col < N);
            const float bcol = (EPI == 0 || !cok) ? 0.f : bias[col];
#pragma unroll
            for (int r = 0; r < 4; ++r) {
                const int row = row0 + wm * 128 + mt * 16 + lq * 4 + r;
                float v = acc[mt][nt][r] + bcol;
                if (EPI == 1) {
                    if (cok) Cb[(size_t)row * N + col] = __float2bfloat16(gelu_f(v));
                } else if (EPI == 2) {
                    if (cok) Cf[(size_t)row * N + col] += v;
                } else {
                    if (cok) Cf[(size_t)row * N + col] = v;
                }
            }
        }
    }
}

// ---------------------------------------------------------------------------
// Encoder weight fold: W_enc[e,k] = enc_base_w[e%896,k] + beta*(B^T A)[e,k]
// out bf16 (3584 x 1024). grid (16, 56).
// ---------------------------------------------------------------------------
__global__ __launch_bounds__(256) void pack_enc_kernel(const float* __restrict__ baseW,
                                                       const float* __restrict__ Aw,
                                                       const float* __restrict__ Bv,
                                                       const float* __restrict__ betap,
                                                       bf16* __restrict__ outp)
{
    __shared__ float Ps[64][68];
    __shared__ float Qs[64][68];
    const int tid = threadIdx.x;
    const int e0 = blockIdx.y * 64;
    const int k0 = blockIdx.x * 64;

    for (int f = tid; f < 1024; f += 256) {
        int r = f >> 4, c4 = (f & 15) << 2;
        *(float4*)&Ps[r][c4] = *(const float4*)(Bv + (size_t)r * ND + e0 + c4);
        *(float4*)&Qs[r][c4] = *(const float4*)(Aw + (size_t)r * IO + k0 + c4);
    }
    __syncthreads();

    const int tx = tid & 15, ty = tid >> 4;
    float acc[4][4];
#pragma unroll
    for (int i = 0; i < 4; ++i)
#pragma unroll
        for (int j = 0; j < 4; ++j) acc[i][j] = 0.f;

#pragma unroll 8
    for (int r = 0; r < 64; ++r) {
        float a[4], b[4];
        *(float4*)a = *(const float4*)&Ps[r][ty * 4];
        *(float4*)b = *(const float4*)&Qs[r][tx * 4];
#pragma unroll
        for (int i = 0; i < 4; ++i)
#pragma unroll
            for (int j = 0; j < 4; ++j) acc[i][j] = fmaf(a[i], b[j], acc[i][j]);
    }

    const float beta = betap[0];
#pragma unroll
    for (int i = 0; i < 4; ++i) {
        const int e = e0 + ty * 4 + i;
        const int d = e % DD;
#pragma unroll
        for (int j = 0; j < 4; ++j) {
            const int k = k0 + tx * 4 + j;
            float v = baseW[(size_t)d * IO + k] + beta * acc[i][j];
            outp[(size_t)e * IO + k] = __float2bfloat16(v);
        }
    }
}

// ---------------------------------------------------------------------------
// QKV bf16 MFMA -> separate Q (t,d), K (t,d), V^T (d,t). grid (3, 8, GQ)
// ---------------------------------------------------------------------------
__global__ __launch_bounds__(256) void qkv_bf16_kernel(
    const bf16* __restrict__ xh,
    const bf16* __restrict__ Wt,
    bf16* __restrict__ Qg,
    bf16* __restrict__ Kg,
    bf16* __restrict__ Vtg,
    const int* __restrict__ phase_p,
    int go)
{
    __shared__ bf16 As[128 * 64];
    __shared__ bf16 Bs[128 * 64];

    const int ph  = phase_p[0] & 3;
    const int zbl = blockIdx.z;
    const int hh  = (go + zbl) % 12;
    const int n   = hh / 3;
    const int k   = hh % 3;
    const int m   = (k == 0) ? n
                  : (k == 1) ? ((n + 2 * (ph & 1)) & 3)
                             : ((n + (ph & 3)) & 3);
    const bf16* A  = xh + (size_t)zbl * (1024 * 128);
    const bf16* Bw = Wt + (size_t)(k * 4 + m) * (384 * 128);

    const int tid  = threadIdx.x;
    const int wave = tid >> 6;
    const int lane = tid & 63;
    const int wm = wave >> 1, wn = wave & 1;
    const int row0 = blockIdx.y * 128;
    const int col0 = blockIdx.x * 128;
    const int lr = lane & 15;
    const int lq = lane >> 4;
    const int srow = lane >> 3;
    const int scol = (lane & 7) * 8;

    f32x4 acc[4][4];
#pragma unroll
    for (int i = 0; i < 4; ++i)
#pragma unroll
        for (int j = 0; j < 4; ++j) acc[i][j] = (f32x4){0.f, 0.f, 0.f, 0.f};

#pragma unroll
    for (int k0 = 0; k0 < 128; k0 += 64) {
#pragma unroll
        for (int j = 0; j < 4; ++j) {
            const int rg = wave * 32 + j * 8;
            __builtin_amdgcn_global_load_lds(
                (const __attribute__((address_space(1))) unsigned int*)
                    (A + (size_t)(row0 + rg + srow) * 128 + k0 + scol),
                (__attribute__((address_space(3))) unsigned int*)(As + rg * 64),
                16, 0, 0);
        }
#pragma unroll
        for (int j = 0; j < 4; ++j) {
            const int rg = wave * 32 + j * 8;
            __builtin_amdgcn_global_load_lds(
                (const __attribute__((address_space(1))) unsigned int*)
                    (Bw + (size_t)(col0 + rg + srow) * 128 + k0 + scol),
                (__attribute__((address_space(3))) unsigned int*)(Bs + rg * 64),
                16, 0, 0);
        }
        __syncthreads();

#pragma unroll
        for (int s = 0; s < 64; s += 32) {
            short8 af[4], bf[4];
#pragma unroll
            for (int mt = 0; mt < 4; ++mt)
                af[mt] = *(const short8*)&As[(wm * 64 + mt * 16 + lr) * 64 + s + lq * 8];
#pragma unroll
            for (int nt = 0; nt < 4; ++nt)
                bf[nt] = *(const short8*)&Bs[(wn * 64 + nt * 16 + lr) * 64 + s + lq * 8];
#pragma unroll
            for (int mt = 0; mt < 4; ++mt)
#pragma unroll
                for (int nt = 0; nt < 4; ++nt)
                    acc[mt][nt] = __builtin_amdgcn_mfma_f32_16x16x32_bf16(
                        af[mt], bf[nt], acc[mt][nt], 0, 0, 0);
        }
        __syncthreads();
    }

    if (col0 < 256) {
        bf16* C = (col0 == 0 ? Qg : Kg) + (size_t)zbl * (1024 * 128);
#pragma unroll
        for (int mt = 0; mt < 4; ++mt)
#pragma unroll
            for (int nt = 0; nt < 4; ++nt) {
                const int col = wn * 64 + nt * 16 + lr;   // local 0..127
#pragma unroll
                for (int r = 0; r < 4; ++r) {
                    const int row = row0 + wm * 64 + mt * 16 + lq * 4 + r;
                    C[(size_t)row * 128 + col] = __float2bfloat16(acc[mt][nt][r]);
                }
            }
    } else {
        bf16* Vt = Vtg + (size_t)zbl * (128 * 1024);
#pragma unroll
        for (int mt = 0; mt < 4; ++mt)
#pragma unroll
            for (int nt = 0; nt < 4; ++nt) {
                const int d = wn * 64 + nt * 16 + lr;
                const int rowb = row0 + wm * 64 + mt * 16 + lq * 4;
                union { bf16 h[4]; uint2 u; } pk;
#pragma unroll
                for (int r = 0; r < 4; ++r)
                    pk.h[r] = __float2bfloat16(acc[mt][nt][r]);
                *(uint2*)(Vt + (size_t)d * 1024 + rowb) = pk.u;
            }
    }
}

// ---------------------------------------------------------------------------
// R12/R13 flash attention: BQ=128, 8 waves (512 thr), persistent blocks + LPT
// queue. K double-buffered, V single-buffered (wait hidden under QK+softmax),
// Ps 128x64. LDS = 32K + 16K + 16K = 64KB -> 2 blocks/CU = 4 waves/SIMD.
// launch_bounds (512,2): VGPR budget 256 (the (512,4) variant spilled to
// scratch: VGPR=64, +380MB HBM traffic, 2x slower). Counted vmcnt; inline-asm
// LDS reads; 3 raw barriers/tile; R8 XOR swizzle retained.
// ---------------------------------------------------------------------------
__global__ __launch_bounds__(512, 2) void flash_bf16_kernel(
    const bf16* __restrict__ Qg,
    const bf16* __restrict__ Kg,
    const bf16* __restrict__ Vtg,
    float* __restrict__ z,
    const int* __restrict__ phase_p,
    int go, int GQ, int* __restrict__ cnt)
{
    __shared__ bf16 Ks[2 * 64 * 128];
    __shared__ bf16 Vs[128 * 64];
    __shared__ bf16 Ps[128 * 64];
    __shared__ int sw;

    const int ph   = phase_p[0] & 3;
    const int tid  = threadIdx.x;
    const int wave = tid >> 6;               // 0..7
    const int lane = tid & 63;
    const int lr = lane & 15;
    const int lq = lane >> 4;
    const int sr4 = lane >> 4, sc4 = (lane & 15) * 8;
    const int sr8 = lane >> 3, sc8 = (lane & 7) * 8;
    const int swz = (lr & 7) << 3;           // read-side swizzle (row&7==lr&7)
    const float sc = 0.08838834764831845f;   // 1/sqrt(128)
    const int nitems = GQ * 8;

    for (;;) {
        __syncthreads();
        if (tid == 0) sw = atomicAdd(cnt, 1);
        __syncthreads();
        const int w = sw;
        if (w >= nitems) return;

        const int wq  = w / GQ;
        const int qy8 = 7 - wq;              // heavy q-tiles first (LPT)
        const int zbl = w - wq * GQ;
        const int zb  = go + zbl;
        const int b   = zb / 12;
        const int hh  = zb % 12;
        const int n   = hh / 3;
        const int ksl = hh % 3;
        const int slot = (ksl == 0) ? 0 : (ksl == 1 ? 1 + (ph & 1) : 3 + (ph & 3));
        const int q0  = qy8 * 128;
        const int NT  = qy8 * 2 + 2;

        const bf16* Qp = Qg  + (size_t)zbl * (1024 * 128);
        const bf16* Kp = Kg  + (size_t)zbl * (1024 * 128);
        const bf16* Vp = Vtg + (size_t)zbl * (128 * 1024);

        // K tile t -> Ks[t&1]: 2 DMA issues/wave (8 waves cover 64 rows)
        auto stageK = [&](int t) {
            const int j0 = t * 64;
            bf16* Kd = Ks + (t & 1) * (64 * 128);
#pragma unroll
            for (int j = 0; j < 2; ++j) {
                const int rg = wave * 8 + j * 4;
                const int krow = rg + sr4;
                const int kcol = sc4 ^ ((krow & 7) << 3);    // pre-swizzled src
                __builtin_amdgcn_global_load_lds(
                    (const __attribute__((address_space(1))) unsigned int*)
                        (Kp + (size_t)(j0 + krow) * 128 + kcol),
                    (__attribute__((address_space(3))) unsigned int*)(Kd + rg * 128),
                    16, 0, 0);
            }
        };
        // V tile t -> Vs (single buffer): 2 DMA issues/wave (128 rows)
        auto stageV = [&](int t) {
            const int j0 = t * 64;
#pragma unroll
            for (int j = 0; j < 2; ++j) {
                const int rg = wave * 16 + j * 8;
                const int vrow = rg + sr8;
                const int vcol = sc8 ^ ((vrow & 7) << 3);    // pre-swizzled src
                __builtin_amdgcn_global_load_lds(
                    (const __attribute__((address_space(1))) unsigned int*)
                        (Vp + (size_t)vrow * 1024 + j0 + vcol),
                    (__attribute__((address_space(3))) unsigned int*)(Vs + rg * 64),
                    16, 0, 0);
            }
        };

        short8 qreg[4];
#pragma unroll
        for (int s = 0; s < 4; ++s)
            qreg[s] = *(const short8*)(Qp + (size_t)(q0 + wave * 16 + lr) * 128
                                       + s * 32 + lq * 8);

        f32x4 accO[8];
        float m_i[4], l_i[4];
#pragma unroll
        for (int j = 0; j < 8; ++j) accO[j] = (f32x4){0.f, 0.f, 0.f, 0.f};
#pragma unroll
        for (int r = 0; r < 4; ++r) { m_i[r] = -1e30f; l_i[r] = 0.f; }

        stageK(0);

        for (int t = 0; t < NT; ++t) {
            const bool more = (t + 1 < NT);
            if (more) stageK(t + 1);
            stageV(t);
            // wait K(t) ready (issued last iter / prologue)
            if (more) asm volatile("s_waitcnt vmcnt(4)" ::: "memory");
            else      asm volatile("s_waitcnt vmcnt(2)" ::: "memory");
            __builtin_amdgcn_s_barrier();
            __builtin_amdgcn_sched_barrier(0);

            const bf16* Kbb = Ks + (t & 1) * (64 * 128);
            const int j0 = t * 64;
            // wave handles rows q0+wave*16..+15; tile fully-masked -> skip
            const bool active = (j0 <= q0 + wave * 16 + 15);

            if (active) {
                // --- QK^T: counted-lgkm pipelined asm ds_reads
                f32x4 accS[4];
#pragma unroll
                for (int nt = 0; nt < 4; ++nt) accS[nt] = (f32x4){0.f, 0.f, 0.f, 0.f};
                short8 bk[2][4];
#pragma unroll
                for (int nt = 0; nt < 4; ++nt)
                    DS_READ_B128(bk[0][nt],
                                 Kbb + (nt * 16 + lr) * 128 + ((lq * 8) ^ swz));
#pragma unroll
                for (int s = 0; s < 4; ++s) {
                    if (s + 1 < 4) {
#pragma unroll
                        for (int nt = 0; nt < 4; ++nt)
                            DS_READ_B128(bk[(s + 1) & 1][nt],
                                         Kbb + (nt * 16 + lr) * 128
                                             + (((s + 1) * 32 + lq * 8) ^ swz));
                        asm volatile("s_waitcnt lgkmcnt(4)" ::: "memory");
                    } else {
                        asm volatile("s_waitcnt lgkmcnt(0)" ::: "memory");
                    }
                    __builtin_amdgcn_sched_barrier(0);
#pragma unroll
                    for (int nt = 0; nt < 4; ++nt)
                        accS[nt] = __builtin_amdgcn_mfma_f32_16x16x32_bf16(
                            qreg[s], bk[s & 1][nt], accS[nt], 0, 0, 0);
                }

                // --- online softmax (wave-private Ps rows, swizzled)
                const bool need_mask = (j0 + 63 > q0 + wave * 16);
#pragma unroll
                for (int r = 0; r < 4; ++r) {
                    const int row = q0 + wave * 16 + lq * 4 + r;
                    float sv[4];
#pragma unroll
                    for (int nt = 0; nt < 4; ++nt) {
                        float v = accS[nt][r] * sc;
                        if (need_mask && (j0 + nt * 16 + lr > row)) v = -1e30f;
                        sv[nt] = v;
                    }
                    float mx = fmaxf(fmaxf(sv[0], sv[1]), fmaxf(sv[2], sv[3]));
#pragma unroll
                    for (int msk = 8; msk; msk >>= 1) mx = fmaxf(mx, __shfl_xor(mx, msk, 16));
                    float mnew = fmaxf(m_i[r], mx);
                    float al   = __expf(m_i[r] - mnew);
                    float rs = 0.f;
#pragma unroll
                    for (int nt = 0; nt < 4; ++nt) {
                        sv[nt] = __expf(sv[nt] - mnew);
                        rs += sv[nt];
                    }
#pragma unroll
                    for (int msk = 8; msk; msk >>= 1) rs += __shfl_xor(rs, msk, 16);
                    l_i[r] = l_i[r] * al + rs;
                    m_i[r] = mnew;
#pragma unroll
                    for (int d8 = 0; d8 < 8; ++d8) accO[d8][r] *= al;
                    const int prow = wave * 16 + lq * 4 + r;
                    const int pswz = (prow & 7) << 3;
#pragma unroll
                    for (int nt = 0; nt < 4; ++nt)
                        Ps[prow * 64 + ((nt * 16 + lr) ^ pswz)] = __float2bfloat16(sv[nt]);
                }
                asm volatile("" ::: "memory");
            }

            // V(t) ready (all waves drain their own V issues, then barrier)
            if (more) asm volatile("s_waitcnt vmcnt(2)" ::: "memory");
            else      asm volatile("s_waitcnt vmcnt(0)" ::: "memory");
            __builtin_amdgcn_s_barrier();
            __builtin_amdgcn_sched_barrier(0);

            if (active) {
                // --- PV: 2 k-slices, double-issued asm reads
                short8 ap[2], bv[2][8];
                DS_READ_B128(ap[0], Ps + (wave * 16 + lr) * 64 + ((lq * 8) ^ swz));
#pragma unroll
                for (int d8 = 0; d8 < 8; ++d8)
                    DS_READ_B128(bv[0][d8],
                                 Vs + (d8 * 16 + lr) * 64 + ((lq * 8) ^ swz));
#pragma unroll
                for (int kv = 0; kv < 2; ++kv) {
                    if (kv == 0) {
                        DS_READ_B128(ap[1],
                                     Ps + (wave * 16 + lr) * 64 + ((32 + lq * 8) ^ swz));
#pragma unroll
                        for (int d8 = 0; d8 < 8; ++d8)
                            DS_READ_B128(bv[1][d8],
                                         Vs + (d8 * 16 + lr) * 64 + ((32 + lq * 8) ^ swz));
                        asm volatile("s_waitcnt lgkmcnt(9)" ::: "memory");
                    } else {
                        asm volatile("s_waitcnt lgkmcnt(0)" ::: "memory");
                    }
                    __builtin_amdgcn_sched_barrier(0);
#pragma unroll
                    for (int d8 = 0; d8 < 8; ++d8)
                        accO[d8] = __builtin_amdgcn_mfma_f32_16x16x32_bf16(
                            ap[kv], bv[kv][d8], accO[d8], 0, 0, 0);
                }
            }

            __builtin_amdgcn_s_barrier();    // all V/K reads done before restage
        }

#pragma unroll
        for (int r = 0; r < 4; ++r) {
            const int t = q0 + wave * 16 + lq * 4 + r;
            const float inv = 1.0f / l_i[r];
            float* dst = z + (size_t)(b * 1024 + t) * ND + n * DD + slot * DH;
#pragma unroll
            for (int d8 = 0; d8 < 8; ++d8)
                dst[d8 * 16 + lr] += accO[d8][r] * inv;
        }
    }
}

// ---------------------------------------------------------------------------
// fp32 -> bf16 elementwise (n4 = n/4)
// ---------------------------------------------------------------------------
__global__ __launch_bounds__(256) void cvt_bf16_kernel(const float* __restrict__ src,
                                                       bf16* __restrict__ dst,
                                                       int n4)
{
    int i = blockIdx.x * 256 + threadIdx.x;
    if (i < n4) {
        float4 v = ((const float4*)src)[i];
        bf16* d = dst + (size_t)i * 4;
        d[0] = __float2bfloat16(v.x);
        d[1] = __float2bfloat16(v.y);
        d[2] = __float2bfloat16(v.z);
        d[3] = __float2bfloat16(v.w);
    }
}

// Wqkv (12,128,384) fp32 -> Wt (12,384,128) bf16
__global__ __launch_bounds__(256) void cvt_wqkv_kernel(const float* __restrict__ W,
                                                       bf16* __restrict__ Wt)
{
    int o = blockIdx.x * 256 + threadIdx.x;
    if (o < 12 * 384 * 128) {
        int i = o / 49152, rem = o % 49152;
        int e = rem / 128, d = rem % 128;
        Wt[o] = __float2bfloat16(W[(size_t)i * 49152 + d * 384 + e]);
    }
}

// ---------------------------------------------------------------------------
// Attention-input LayerNorm -> bf16 head-major xh. grid = GQ*256 blocks.
// ---------------------------------------------------------------------------
__global__ __launch_bounds__(256) void ln_attn_kernel(const float* __restrict__ z,
                                                      bf16* __restrict__ xh,
                                                      const float* __restrict__ scale,
                                                      const float* __restrict__ bias,
                                                      const int* __restrict__ phase_p,
                                                      int bt0)
{
    const int ph   = phase_p[0] & 3;
    const int lane = threadIdx.x & 63;
    const int row  = blockIdx.x * 4 + (threadIdx.x >> 6);
    const int k    = row % 3;
    const int n    = (row / 3) & 3;
    const int btl  = row / 12;
    const int slot = (k == 0) ? 0 : (k == 1 ? 1 + (ph & 1) : 3 + (ph & 3));
    const int bt   = bt0 + btl;

    const float* src = z + (size_t)bt * ND + n * DD + slot * DH + lane * 2;
    float2 v = *(const float2*)src;
    float s = v.x + v.y;
    float q = v.x * v.x + v.y * v.y;
#pragma unroll
    for (int m = 32; m; m >>= 1) { s += __shfl_xor(s, m); q += __shfl_xor(q, m); }
    float mu  = s * (1.0f / 128.0f);
    float var = q * (1.0f / 128.0f) - mu * mu;
    float r   = rsqrtf(var + 1e-5f);

    float2 sc2 = *(const float2*)(scale + lane * 2);
    float2 bi2 = *(const float2*)(bias + lane * 2);
    const int bl = btl >> 10, t = btl & 1023;
    union { bf16 h[2]; unsigned int u; } pk;
    pk.h[0] = __float2bfloat16((v.x - mu) * r * sc2.x + bi2.x);
    pk.h[1] = __float2bfloat16((v.y - mu) * r * sc2.y + bi2.y);
    *(unsigned int*)(xh + (size_t)((bl * 12 + n * 3 + k) * 1024 + t) * DH + lane * 2) = pk.u;
}

// ---------------------------------------------------------------------------
// Row LayerNorm, bf16 output. W=896 (mixer input) / W=3584 (decoder input).
// ---------------------------------------------------------------------------
template<int W>
__global__ __launch_bounds__(256) void ln_row_bf16_kernel(const float* __restrict__ in,
                                                          bf16* __restrict__ outp,
                                                          const float* __restrict__ scale,
                                                          const float* __restrict__ bias)
{
    constexpr int NIT = (W + 255) / 256;
    const int row = blockIdx.x;
    const int tid = threadIdx.x;
    const float* rp = in + (size_t)row * W;

    float v[NIT];
    float s = 0.f, q = 0.f;
#pragma unroll
    for (int i = 0; i < NIT; ++i) {
        int idx = tid + i * 256;
        if (idx < W) { float t = rp[idx]; v[i] = t; s += t; q += t * t; }
        else v[i] = 0.f;
    }
#pragma unroll
    for (int m = 32; m; m >>= 1) { s += __shfl_xor(s, m); q += __shfl_xor(q, m); }
    __shared__ float ss[4], sq[4];
    if ((tid & 63) == 0) { ss[tid >> 6] = s; sq[tid >> 6] = q; }
    __syncthreads();
    s = ss[0] + ss[1] + ss[2] + ss[3];
    q = sq[0] + sq[1] + sq[2] + sq[3];
    float mu  = s * (1.0f / W);
    float var = q * (1.0f / W) - mu * mu;
    float r   = rsqrtf(var + 1e-5f);

    bf16* op = outp + (size_t)row * W;
#pragma unroll
    for (int i = 0; i < NIT; ++i) {
        int idx = tid + i * 256;
        if (idx < W)
            op[idx] = __float2bfloat16((v[i] - mu) * r * scale[idx] + bias[idx]);
    }
}

// ---------------------------------------------------------------------------
// Launcher. ws-aware (ws>=205 MB proven by R6's CH=8192 run passing):
//   attn: GQ=96 (102 MB in R) if ws>=230 MB else GQ=48 (51.5 MB).
//   mixer: CH=8192 (86.2 MB) if ws>=205 MB else 4096 (49.5 MB).
//   decoder: zb 58.7 MB + dec_down_pad 0.92 MB + t1 2.1 MB in R (fits 88 MB).
// ---------------------------------------------------------------------------
extern "C" void kernel_launch(void* const* d_in, const int* in_sizes, int n_in,
                              void* d_out, int out_size, void* d_ws, size_t ws_size,
                              hipStream_t stream)
{
    const float* x          = (const float*)d_in[0];
    const float* enc_base_w = (const float*)d_in[1];
    const float* enc_A_w    = (const float*)d_in[2];
    const float* enc_B      = (const float*)d_in[3];
    const float* enc_beta   = (const float*)d_in[4];
    const float* Wqkv       = (const float*)d_in[5];
    const float* ln_attn_s  = (const float*)d_in[6];
    const float* ln_attn_b  = (const float*)d_in[7];
    const float* ln_mix_s   = (const float*)d_in[8];
    const float* ln_mix_b   = (const float*)d_in[9];
    const float* w1         = (const float*)d_in[10];
    const float* b1         = (const float*)d_in[11];
    const float* w2         = (const float*)d_in[12];
    const float* b2         = (const float*)d_in[13];
    const float* dec_ln_s   = (const float*)d_in[14];
    const float* dec_ln_b   = (const float*)d_in[15];
    const float* dec_down   = (const float*)d_in[16];
    const float* dec_up     = (const float*)d_in[17];
    const int*   phase_p    = (const int*)d_in[18];
    float* out = (float*)d_out;

    float* ws = (float*)d_ws;
    float* z  = ws;                                  // 8192*3584 fp32 (persistent)
    float* R  = ws + (size_t)BT * ND;

    const int GQ = (ws_size >= 230000000UL) ? 96 : 48;
    const int CH = (ws_size >= 205000000UL) ? 8192 : 4096;

    // encoder phase
    bf16* xb   = (bf16*)R;                           // 8192*1024
    bf16* Wenc = xb + (size_t)BT * IO;               // 3584*1024
    // attention phase
    bf16* Wt   = (bf16*)R;                           // 12*384*128
    bf16* xh_b = Wt + 12 * 384 * 128;                // GQ*1024*128
    bf16* Qb   = xh_b + (size_t)GQ * 1024 * 128;     // GQ*1024*128
    bf16* Kb   = Qb + (size_t)GQ * 1024 * 128;       // GQ*1024*128
    bf16* Vtg  = Kb + (size_t)GQ * 1024 * 128;       // GQ*128*1024
    int*  cnt  = (int*)(Vtg + (size_t)GQ * 128 * 1024);  // 2 ints (work queue)
    // mixer phase
    bf16* w1b  = (bf16*)R;                           // 3584*896
    bf16* w2b  = w1b + (size_t)HID * DD;             // 896*3584
    bf16* hm   = w2b + (size_t)DD * HID;             // CH*896
    bf16* gbuf = hm + (size_t)CH * DD;               // CH*3584
    // dec phase
    bf16*  zb  = (bf16*)R;                           // 8192*3584 bf16 (LN'd)
    bf16*  ddp = zb + (size_t)BT * ND;               // 128*3584 bf16 (padded W)
    float* t1  = (float*)(ddp + 128 * ND);           // 8192*64 fp32

    // --- Encoder: fold low-rank into W_enc, then one bf16 GEMM into z
    cvt_bf16_kernel<<<dim3(8192), 256, 0, stream>>>(x, xb, BT * IO / 4);
    pack_enc_kernel<<<dim3(16, 56), 256, 0, stream>>>(enc_base_w, enc_A_w, enc_B,
                                                      enc_beta, Wenc);
    gemm_bf16_256<256, 0><<<dim3(14, 32), 512, 0, stream>>>(xb, Wenc, z, nullptr,
                                                            ND, IO, nullptr);

    // --- Attention (bf16 MFMA), GQ heads per group
    cvt_wqkv_kernel<<<dim3(2304), 256, 0, stream>>>(Wqkv, Wt);
    hipMemsetAsync(cnt, 0, 2 * sizeof(int), stream);
    const int ngroups = 96 / GQ;
    for (int g = 0; g < ngroups; ++g) {
        ln_attn_kernel<<<dim3(GQ * 256), 256, 0, stream>>>(z, xh_b, ln_attn_s,
                                                           ln_attn_b, phase_p,
                                                           g * (GQ / 12) * 1024);
        qkv_bf16_kernel<<<dim3(3, 8, GQ), 256, 0, stream>>>(xh_b, Wt, Qb, Kb, Vtg,
                                                            phase_p, g * GQ);
        flash_bf16_kernel<<<dim3(512), 512, 0, stream>>>(Qb, Kb, Vtg, z,
                                                         phase_p, g * GQ, GQ,
                                                         cnt + g);
    }

    // --- Mixer MLP on bf16 MFMA, chunks of CH rows (of 32768 x 896)
    cvt_bf16_kernel<<<dim3(3136), 256, 0, stream>>>(w1, w1b, HID * DD / 4);
    cvt_bf16_kernel<<<dim3(3136), 256, 0, stream>>>(w2, w2b, DD * HID / 4);
    for (int c = 0; c < 32768 / CH; ++c) {
        float* zc = z + (size_t)c * CH * DD;
        ln_row_bf16_kernel<896><<<dim3(CH), 256, 0, stream>>>(zc, hm,
                                                              ln_mix_s, ln_mix_b);
        gemm_bf16_256<256, 1><<<dim3(14, CH / 256), 512, 0, stream>>>(
            hm, w1b, nullptr, gbuf, HID, DD, b1);
        gemm_bf16_256<128, 2><<<dim3(7, CH / 256), 512, 0, stream>>>(
            gbuf, w2b, zc, nullptr, DD, HID, b2);
    }

    // --- Decoder: LN -> bf16, MFMA down-projection (padded 128-col, 64 kept),
    // fp32 up-projection.
    ln_row_bf16_kernel<3584><<<dim3(8192), 256, 0, stream>>>(z, zb,
                                                             dec_ln_s, dec_ln_b);
    hipMemsetAsync(ddp + (size_t)64 * ND, 0, (size_t)64 * ND * sizeof(bf16),
                   stream);
    cvt_bf16_kernel<<<dim3(224), 256, 0, stream>>>(dec_down, ddp, 64 * ND / 4);
    gemm_bf16_256<128, 0><<<dim3(1, 32), 512, 0, stream>>>(zb, ddp, t1, nullptr,
                                                           RK, ND, nullptr);
    gemm_kernel<128, 128, 16, 8, 8>
        <<<dim3(8, 64), 256, 0, stream>>>(t1, dec_up, out, IO, RK);
}

// Round 8
// 1184.008 us; speedup vs baseline: 1.0354x; 1.0354x over previous
//
#include <hip/hip_runtime.h>
#include <hip/hip_bf16.h>
#include <math.h>

// ---------------------------------------------------------------------------
// Morpher forward. All large GEMMs bf16 MFMA; encoder low-rank folded;
// flash attention Q-in-registers.
// R8: flash LDS XOR-swizzle. R9: gemm_bf16_256 deep pipeline (counted vmcnt).
// R10: inline-asm ds_read_b128 (compiler LDS-DMA alias tracking re-inserted
//      vmcnt(0) -> depth-0; asm reads are opaque).
// R11: flash dbuf + counted vmcnt. R12: flash BQ=128 8-wave blocks.
// R13: launch_bounds (512,2) fixes VGPR=64 scratch spill.
// R14: decoder down-projection onto MFMA path (bf16 LN, padded weights).
// R15: (a) gemm_bf16_256 lgkm-split dual MFMA clusters (overlap A-high read
//      latency under first cluster); (b) split-K via gridDim.z + EPI=3
//      atomicAdd for the 32-block decoder GEMM -> (1,32,8)=256 blocks;
//      (c) flash: static balanced 5-group schedule (16/16/16/16/8 tiles per
//      block, grid GQ*5) replacing the queue whose 384 items over 512 blocks
//      left worst CUs with ~32 tiles vs 13.5 avg.
// Shapes: B=8 T=1024 (BT=8192), N=4, K=3, S=7, DH=128, D=896, ND=3584,
// IO=1024, RANK=64, HIDDEN=3584.
// ---------------------------------------------------------------------------

#define BT   8192
#define DH   128
#define DD   896
#define ND   3584
#define IO   1024
#define RK   64
#define HID  3584

typedef __attribute__((ext_vector_type(8))) short short8;
typedef __attribute__((ext_vector_type(4))) float f32x4;
typedef __hip_bfloat16 bf16;

// inline-asm LDS read: opaque to SIInsertWaitcnts' LDS-DMA tracking.
#define DS_READ_B128(dst, p)                                                  \
    asm volatile("ds_read_b128 %0, %1"                                        \
                 : "=v"(dst)                                                  \
                 : "v"((const __attribute__((address_space(3))) bf16*)(p)))

// Fast gelu: exact-form 0.5x(1+erf(x/sqrt2)) with A&S 7.1.26 erf
__device__ __forceinline__ float gelu_f(float v)
{
    float u = v * 0.70710678118654752f;
    float a = fabsf(u);
    float t = __builtin_amdgcn_rcpf(1.0f + 0.3275911f * a);
    float p = t * (0.254829592f + t * (-0.284496736f + t * (1.421413741f +
              t * (-1.453152027f + t * 1.061405429f))));
    float er = 1.0f - p * __expf(-u * u);
    er = copysignf(er, u);
    return 0.5f * v * (1.0f + er);
}

// ---------------------------------------------------------------------------
// fp32 tiled GEMM (decoder up-projection only). C = A @ B^T, B (N x Kd) rm.
// ---------------------------------------------------------------------------
template<int BM, int BN, int BK, int TM, int TN>
__global__ __launch_bounds__(256) void gemm_kernel(const float* __restrict__ A,
                                                   const float* __restrict__ B,
                                                   float* __restrict__ C,
                                                   int N, int Kd)
{
    constexpr int THREADS = (BM / TM) * (BN / TN);
    constexpr int LDA = BM + 4;
    constexpr int LDB = BN + 4;
    __shared__ float As[BK][LDA];
    __shared__ float Bs[BK][LDB];

    const int tid = threadIdx.x;
    constexpr int NX = BN / TN;
    const int tx = tid % NX;
    const int ty = tid / NX;
    const int row0 = blockIdx.y * BM;
    const int col0 = blockIdx.x * BN;

    float acc[TM][TN];
#pragma unroll
    for (int i = 0; i < TM; ++i)
#pragma unroll
        for (int j = 0; j < TN; ++j) acc[i][j] = 0.f;

    for (int k0 = 0; k0 < Kd; k0 += BK) {
        constexpr int AF4 = BM * BK / 4;
        for (int f = tid; f < AF4; f += THREADS) {
            int r  = f / (BK / 4);
            int c4 = (f % (BK / 4)) * 4;
            float4 v = *(const float4*)(A + (size_t)(row0 + r) * Kd + k0 + c4);
            As[c4 + 0][r] = v.x; As[c4 + 1][r] = v.y;
            As[c4 + 2][r] = v.z; As[c4 + 3][r] = v.w;
        }
        constexpr int BF4 = BN * BK / 4;
        for (int f = tid; f < BF4; f += THREADS) {
            int r  = f / (BK / 4);
            int c4 = (f % (BK / 4)) * 4;
            float4 v = *(const float4*)(B + (size_t)(col0 + r) * Kd + k0 + c4);
            Bs[c4 + 0][r] = v.x; Bs[c4 + 1][r] = v.y;
            Bs[c4 + 2][r] = v.z; Bs[c4 + 3][r] = v.w;
        }
        __syncthreads();

#pragma unroll
        for (int kk = 0; kk < BK; ++kk) {
            float a[TM], b[TN];
#pragma unroll
            for (int i = 0; i < TM; i += 4)
                *(float4*)&a[i] = *(const float4*)&As[kk][ty * TM + i];
#pragma unroll
            for (int j = 0; j < TN; j += 4)
                *(float4*)&b[j] = *(const float4*)&Bs[kk][tx * TN + j];
#pragma unroll
            for (int i = 0; i < TM; ++i)
#pragma unroll
                for (int j = 0; j < TN; ++j)
                    acc[i][j] = fmaf(a[i], b[j], acc[i][j]);
        }
        __syncthreads();
    }

    const int crow = row0 + ty * TM;
    const int ccol = col0 + tx * TN;
#pragma unroll
    for (int i = 0; i < TM; ++i) {
        float* cp = C + (size_t)(crow + i) * N + ccol;
#pragma unroll
        for (int j = 0; j < TN; ++j) cp[j] = acc[i][j];
    }
}

// ---------------------------------------------------------------------------
// R9/R10/R15: bf16 MFMA GEMM, 256xBN tile, 8 waves (512 thr), C = A @ B^T.
// LDS ring of 4 K-half slots, depth-3 prefetch via global_load_lds w16,
// counted vmcnt, inline-asm ds_read_b128 fragments, setprio MFMA clusters,
// XCD-chunked block swizzle. 2 barriers per K-half.
// R15: lgkm-split: all 12 reads issued, lgkmcnt(4) -> MFMA mt0-3 (A-high
// reads in flight), lgkmcnt(0) -> MFMA mt4-7. Split-K via gridDim.z:
// klen = Kd/segs, kbeg = z*klen (row stride stays Kd).
//  EPI 0: Cf = acc ; 1: Cb = bf16(gelu(acc+bias)) ; 2: Cf += acc+bias ;
//  EPI 3: atomicAdd(Cf, acc)   (split-K, C pre-zeroed)
// ---------------------------------------------------------------------------
template<int BN, int EPI>
__global__ __launch_bounds__(512, 2) void gemm_bf16_256(
    const bf16* __restrict__ A,
    const bf16* __restrict__ B,
    float* __restrict__ Cf,
    bf16* __restrict__ Cb,
    int N, int Kd,
    const float* __restrict__ bias)
{
    constexpr int NR    = BN / 64;        // n-frags per wave (4 or 2)
    constexpr int WTN   = 16 * NR;        // wave tile cols
    constexpr int ASLOT = 256 * 32;       // elements per A K-half slot
    constexpr int BSLOT = BN * 32;
    __shared__ bf16 As[4 * ASLOT];
    __shared__ bf16 Bs[4 * BSLOT];

    const int tid  = threadIdx.x;
    const int wave = tid >> 6;
    const int lane = tid & 63;
    const int wm = wave >> 2, wn = wave & 3;
    const int lr = lane & 15, lq = lane >> 4;

    // T1: XCD-chunked block swizzle (nwg % 8 == 0 at every call site)
    const int gx  = gridDim.x;
    int fid = blockIdx.y * gx + blockIdx.x;
    const int cpx = (gx * gridDim.y) >> 3;
    fid = (fid & 7) * cpx + (fid >> 3);
    const int row0 = (fid / gx) * 256;
    const int col0 = (fid % gx) * BN;

    // split-K (gridDim.z segments; z==1 -> whole K)
    const int klen = Kd / (int)gridDim.z;
    const int kbeg = blockIdx.z * klen;

    // staging per-lane constants (16 rows x 64 B per wave-issue)
    const int sr  = lane >> 2;                               // 0..15
    const int scs = (((lane & 3) ^ ((lane >> 3) & 3)) << 3); // swizzled src col
    const bf16* Ag = A + (size_t)(row0 + sr) * Kd + kbeg + scs;
    const bf16* Bg = B + (size_t)(col0 + sr) * Kd + kbeg + scs;

    // read-side per-lane swizzle (row&15 == lr on every read path)
    const int scox = (lq * 8) ^ (((lr >> 1) & 3) << 3);

    f32x4 acc[8][NR];
#pragma unroll
    for (int i = 0; i < 8; ++i)
#pragma unroll
        for (int j = 0; j < NR; ++j) acc[i][j] = (f32x4){0.f, 0.f, 0.f, 0.f};

    const int NH = klen >> 5;   // number of K-halves (>= 14 at all call sites)

    auto stage = [&](int h) {
        const int slot = h & 3;
#pragma unroll
        for (int i = 0; i < 2; ++i) {
            const int rg = (i * 8 + wave) * 16;
            __builtin_amdgcn_global_load_lds(
                (const __attribute__((address_space(1))) unsigned int*)
                    (Ag + (size_t)rg * Kd + h * 32),
                (__attribute__((address_space(3))) unsigned int*)
                    (As + slot * ASLOT + rg * 32),
                16, 0, 0);
        }
#pragma unroll
        for (int i = 0; i < BN / 128; ++i) {
            const int rg = (i * 8 + wave) * 16;
            __builtin_amdgcn_global_load_lds(
                (const __attribute__((address_space(1))) unsigned int*)
                    (Bg + (size_t)rg * Kd + h * 32),
                (__attribute__((address_space(3))) unsigned int*)
                    (Bs + slot * BSLOT + rg * 32),
                16, 0, 0);
        }
    };

    // prologue: 3 K-halves in flight
    stage(0); stage(1); stage(2);

    for (int h = 0; h < NH; ++h) {
        if (h + 3 < NH) stage(h + 3);

        // counted vmcnt: wait only for stage(h)'s loads (oldest LPH).
        const int ahead = NH - 1 - h;
        if constexpr (BN == 256) {   // LPH = 4
            if (ahead >= 3)      asm volatile("s_waitcnt vmcnt(12)" ::: "memory");
            else if (ahead == 2) asm volatile("s_waitcnt vmcnt(8)"  ::: "memory");
            else if (ahead == 1) asm volatile("s_waitcnt vmcnt(4)"  ::: "memory");
            else                 asm volatile("s_waitcnt vmcnt(0)"  ::: "memory");
        } else {                     // LPH = 3
            if (ahead >= 3)      asm volatile("s_waitcnt vmcnt(9)"  ::: "memory");
            else if (ahead == 2) asm volatile("s_waitcnt vmcnt(6)"  ::: "memory");
            else if (ahead == 1) asm volatile("s_waitcnt vmcnt(3)"  ::: "memory");
            else                 asm volatile("s_waitcnt vmcnt(0)"  ::: "memory");
        }
        __builtin_amdgcn_s_barrier();            // all waves' half-h data in LDS

        const bf16* Ab = As + (h & 3) * ASLOT;
        const bf16* Bb = Bs + (h & 3) * BSLOT;

        short8 bfr[NR], afr[8];
#pragma unroll
        for (int nt = 0; nt < NR; ++nt)
            DS_READ_B128(bfr[nt], Bb + (wn * WTN + nt * 16 + lr) * 32 + scox);
#pragma unroll
        for (int mt = 0; mt < 8; ++mt)
            DS_READ_B128(afr[mt], Ab + (wm * 128 + mt * 16 + lr) * 32 + scox);

        // R15: wait only bfr + afr0-3 (leave last 4 A-reads in flight)
        asm volatile("s_waitcnt lgkmcnt(4)" ::: "memory");
        __builtin_amdgcn_sched_barrier(0);       // rule #18: pin MFMAs below wait

        __builtin_amdgcn_s_setprio(1);
#pragma unroll
        for (int mt = 0; mt < 4; ++mt)
#pragma unroll
            for (int nt = 0; nt < NR; ++nt)
                acc[mt][nt] = __builtin_amdgcn_mfma_f32_16x16x32_bf16(
                    afr[mt], bfr[nt], acc[mt][nt], 0, 0, 0);
        __builtin_amdgcn_s_setprio(0);

        asm volatile("s_waitcnt lgkmcnt(0)" ::: "memory");
        __builtin_amdgcn_sched_barrier(0);

        __builtin_amdgcn_s_setprio(1);
#pragma unroll
        for (int mt = 4; mt < 8; ++mt)
#pragma unroll
            for (int nt = 0; nt < NR; ++nt)
                acc[mt][nt] = __builtin_amdgcn_mfma_f32_16x16x32_bf16(
                    afr[mt], bfr[nt], acc[mt][nt], 0, 0, 0);
        __builtin_amdgcn_s_setprio(0);

        __builtin_amdgcn_s_barrier();            // all reads of slot h&3 done
    }

#pragma unroll
    for (int mt = 0; mt < 8; ++mt) {
#pragma unroll
        for (int nt = 0; nt < NR; ++nt) {
            const int col = col0 + wn * WTN + nt * 16 + lr;
            const bool cok = (col < N);
            const float bcol = (EPI == 0 || EPI == 3 || !cok) ? 0.f : bias[col];
#pragma unroll
            for (int r = 0; r < 4; ++r) {
                const int row = row0 + wm * 128 + mt * 16 + lq * 4 + r;
                float v = acc[mt][nt][r] + bcol;
                if (EPI == 1) {
                    if (cok) Cb[(size_t)row * N + col] = __float2bfloat16(gelu_f(v));
                } else if (EPI == 2) {
                    if (cok) Cf[(size_t)row * N + col] += v;
                } else if (EPI == 3) {
                    if (cok) atomicAdd(Cf + (size_t)row * N + col, v);
                } else {
                    if (cok) Cf[(size_t)row * N + col] = v;
                }
            }
        }
    }
}

// ---------------------------------------------------------------------------
// Encoder weight fold: W_enc[e,k] = enc_base_w[e%896,k] + beta*(B^T A)[e,k]
// out bf16 (3584 x 1024). grid (16, 56).
// ---------------------------------------------------------------------------
__global__ __launch_bounds__(256) void pack_enc_kernel(const float* __restrict__ baseW,
                                                       const float* __restrict__ Aw,
                                                       const float* __restrict__ Bv,
                                                       const float* __restrict__ betap,
                                                       bf16* __restrict__ outp)
{
    __shared__ float Ps[64][68];
    __shared__ float Qs[64][68];
    const int tid = threadIdx.x;
    const int e0 = blockIdx.y * 64;
    const int k0 = blockIdx.x * 64;

    for (int f = tid; f < 1024; f += 256) {
        int r = f >> 4, c4 = (f & 15) << 2;
        *(float4*)&Ps[r][c4] = *(const float4*)(Bv + (size_t)r * ND + e0 + c4);
        *(float4*)&Qs[r][c4] = *(const float4*)(Aw + (size_t)r * IO + k0 + c4);
    }
    __syncthreads();

    const int tx = tid & 15, ty = tid >> 4;
    float acc[4][4];
#pragma unroll
    for (int i = 0; i < 4; ++i)
#pragma unroll
        for (int j = 0; j < 4; ++j) acc[i][j] = 0.f;

#pragma unroll 8
    for (int r = 0; r < 64; ++r) {
        float a[4], b[4];
        *(float4*)a = *(const float4*)&Ps[r][ty * 4];
        *(float4*)b = *(const float4*)&Qs[r][tx * 4];
#pragma unroll
        for (int i = 0; i < 4; ++i)
#pragma unroll
            for (int j = 0; j < 4; ++j) acc[i][j] = fmaf(a[i], b[j], acc[i][j]);
    }

    const float beta = betap[0];
#pragma unroll
    for (int i = 0; i < 4; ++i) {
        const int e = e0 + ty * 4 + i;
        const int d = e % DD;
#pragma unroll
        for (int j = 0; j < 4; ++j) {
            const int k = k0 + tx * 4 + j;
            float v = baseW[(size_t)d * IO + k] + beta * acc[i][j];
            outp[(size_t)e * IO + k] = __float2bfloat16(v);
        }
    }
}

// ---------------------------------------------------------------------------
// QKV bf16 MFMA -> separate Q (t,d), K (t,d), V^T (d,t). grid (3, 8, GQ)
// ---------------------------------------------------------------------------
__global__ __launch_bounds__(256) void qkv_bf16_kernel(
    const bf16* __restrict__ xh,
    const bf16* __restrict__ Wt,
    bf16* __restrict__ Qg,
    bf16* __restrict__ Kg,
    bf16* __restrict__ Vtg,
    const int* __restrict__ phase_p,
    int go)
{
    __shared__ bf16 As[128 * 64];
    __shared__ bf16 Bs[128 * 64];

    const int ph  = phase_p[0] & 3;
    const int zbl = blockIdx.z;
    const int hh  = (go + zbl) % 12;
    const int n   = hh / 3;
    const int k   = hh % 3;
    const int m   = (k == 0) ? n
                  : (k == 1) ? ((n + 2 * (ph & 1)) & 3)
                             : ((n + (ph & 3)) & 3);
    const bf16* A  = xh + (size_t)zbl * (1024 * 128);
    const bf16* Bw = Wt + (size_t)(k * 4 + m) * (384 * 128);

    const int tid  = threadIdx.x;
    const int wave = tid >> 6;
    const int lane = tid & 63;
    const int wm = wave >> 1, wn = wave & 1;
    const int row0 = blockIdx.y * 128;
    const int col0 = blockIdx.x * 128;
    const int lr = lane & 15;
    const int lq = lane >> 4;
    const int srow = lane >> 3;
    const int scol = (lane & 7) * 8;

    f32x4 acc[4][4];
#pragma unroll
    for (int i = 0; i < 4; ++i)
#pragma unroll
        for (int j = 0; j < 4; ++j) acc[i][j] = (f32x4){0.f, 0.f, 0.f, 0.f};

#pragma unroll
    for (int k0 = 0; k0 < 128; k0 += 64) {
#pragma unroll
        for (int j = 0; j < 4; ++j) {
            const int rg = wave * 32 + j * 8;
            __builtin_amdgcn_global_load_lds(
                (const __attribute__((address_space(1))) unsigned int*)
                    (A + (size_t)(row0 + rg + srow) * 128 + k0 + scol),
                (__attribute__((address_space(3))) unsigned int*)(As + rg * 64),
                16, 0, 0);
        }
#pragma unroll
        for (int j = 0; j < 4; ++j) {
            const int rg = wave * 32 + j * 8;
            __builtin_amdgcn_global_load_lds(
                (const __attribute__((address_space(1))) unsigned int*)
                    (Bw + (size_t)(col0 + rg + srow) * 128 + k0 + scol),
                (__attribute__((address_space(3))) unsigned int*)(Bs + rg * 64),
                16, 0, 0);
        }
        __syncthreads();

#pragma unroll
        for (int s = 0; s < 64; s += 32) {
            short8 af[4], bf[4];
#pragma unroll
            for (int mt = 0; mt < 4; ++mt)
                af[mt] = *(const short8*)&As[(wm * 64 + mt * 16 + lr) * 64 + s + lq * 8];
#pragma unroll
            for (int nt = 0; nt < 4; ++nt)
                bf[nt] = *(const short8*)&Bs[(wn * 64 + nt * 16 + lr) * 64 + s + lq * 8];
#pragma unroll
            for (int mt = 0; mt < 4; ++mt)
#pragma unroll
                for (int nt = 0; nt < 4; ++nt)
                    acc[mt][nt] = __builtin_amdgcn_mfma_f32_16x16x32_bf16(
                        af[mt], bf[nt], acc[mt][nt], 0, 0, 0);
        }
        __syncthreads();
    }

    if (col0 < 256) {
        bf16* C = (col0 == 0 ? Qg : Kg) + (size_t)zbl * (1024 * 128);
#pragma unroll
        for (int mt = 0; mt < 4; ++mt)
#pragma unroll
            for (int nt = 0; nt < 4; ++nt) {
                const int col = wn * 64 + nt * 16 + lr;   // local 0..127
#pragma unroll
                for (int r = 0; r < 4; ++r) {
                    const int row = row0 + wm * 64 + mt * 16 + lq * 4 + r;
                    C[(size_t)row * 128 + col] = __float2bfloat16(acc[mt][nt][r]);
                }
            }
    } else {
        bf16* Vt = Vtg + (size_t)zbl * (128 * 1024);
#pragma unroll
        for (int mt = 0; mt < 4; ++mt)
#pragma unroll
            for (int nt = 0; nt < 4; ++nt) {
                const int d = wn * 64 + nt * 16 + lr;
                const int rowb = row0 + wm * 64 + mt * 16 + lq * 4;
                union { bf16 h[4]; uint2 u; } pk;
#pragma unroll
                for (int r = 0; r < 4; ++r)
                    pk.h[r] = __float2bfloat16(acc[mt][nt][r]);
                *(uint2*)(Vt + (size_t)d * 1024 + rowb) = pk.u;
            }
    }
}

// ---------------------------------------------------------------------------
// R12/R13/R15 flash attention: BQ=128, 8 waves (512 thr). Static balanced
// 5-group schedule (grid GQ*5): grp 0..4 -> q-tiles {7},{6,0},{5,1},{4,2},{3}
// = 16/16/16/16/8 kv-tiles per block (constant work, no queue). K dbuf,
// V single-buffered, Ps 128x64; 64KB LDS; counted vmcnt; inline-asm LDS
// reads; 3 raw barriers/tile; R8 XOR swizzle.
// ---------------------------------------------------------------------------
__global__ __launch_bounds__(512, 2) void flash_bf16_kernel(
    const bf16* __restrict__ Qg,
    const bf16* __restrict__ Kg,
    const bf16* __restrict__ Vtg,
    float* __restrict__ z,
    const int* __restrict__ phase_p,
    int go, int GQ)
{
    __shared__ bf16 Ks[2 * 64 * 128];
    __shared__ bf16 Vs[128 * 64];
    __shared__ bf16 Ps[128 * 64];

    const int ph   = phase_p[0] & 3;
    const int tid  = threadIdx.x;
    const int wave = tid >> 6;               // 0..7
    const int lane = tid & 63;
    const int lr = lane & 15;
    const int lq = lane >> 4;
    const int sr4 = lane >> 4, sc4 = (lane & 15) * 8;
    const int sr8 = lane >> 3, sc8 = (lane & 7) * 8;
    const int swz = (lr & 7) << 3;           // read-side swizzle (row&7==lr&7)
    const float sc = 0.08838834764831845f;   // 1/sqrt(128)

    const int zbl = blockIdx.x % GQ;         // head (local in group)
    const int grp = blockIdx.x / GQ;         // 0..4
    const int zb  = go + zbl;
    const int b   = zb / 12;
    const int hh  = zb % 12;
    const int n   = hh / 3;
    const int ksl = hh % 3;
    const int slot = (ksl == 0) ? 0 : (ksl == 1 ? 1 + (ph & 1) : 3 + (ph & 3));

    const bf16* Qp = Qg  + (size_t)zbl * (1024 * 128);
    const bf16* Kp = Kg  + (size_t)zbl * (1024 * 128);
    const bf16* Vp = Vtg + (size_t)zbl * (128 * 1024);

    // K tile t -> Ks[t&1]: 2 DMA issues/wave (8 waves cover 64 rows)
    auto stageK = [&](int t) {
        const int j0 = t * 64;
        bf16* Kd = Ks + (t & 1) * (64 * 128);
#pragma unroll
        for (int j = 0; j < 2; ++j) {
            const int rg = wave * 8 + j * 4;
            const int krow = rg + sr4;
            const int kcol = sc4 ^ ((krow & 7) << 3);    // pre-swizzled src
            __builtin_amdgcn_global_load_lds(
                (const __attribute__((address_space(1))) unsigned int*)
                    (Kp + (size_t)(j0 + krow) * 128 + kcol),
                (__attribute__((address_space(3))) unsigned int*)(Kd + rg * 128),
                16, 0, 0);
        }
    };
    // V tile t -> Vs (single buffer): 2 DMA issues/wave (128 rows)
    auto stageV = [&](int t) {
        const int j0 = t * 64;
#pragma unroll
        for (int j = 0; j < 2; ++j) {
            const int rg = wave * 16 + j * 8;
            const int vrow = rg + sr8;
            const int vcol = sc8 ^ ((vrow & 7) << 3);    // pre-swizzled src
            __builtin_amdgcn_global_load_lds(
                (const __attribute__((address_space(1))) unsigned int*)
                    (Vp + (size_t)vrow * 1024 + j0 + vcol),
                (__attribute__((address_space(3))) unsigned int*)(Vs + rg * 64),
                16, 0, 0);
        }
    };

    // static balanced schedule: groups {7},{6,0},{5,1},{4,2},{3}
    const int qa_t[5] = {7, 6, 5, 4, 3};
    const int qb_t[5] = {-1, 0, 1, 2, -1};

    for (int part = 0; part < 2; ++part) {
        const int qy8 = (part == 0) ? qa_t[grp] : qb_t[grp];
        if (qy8 < 0) break;                  // uniform per block (grp-based)
        const int q0  = qy8 * 128;
        const int NT  = qy8 * 2 + 2;

        short8 qreg[4];
#pragma unroll
        for (int s = 0; s < 4; ++s)
            qreg[s] = *(const short8*)(Qp + (size_t)(q0 + wave * 16 + lr) * 128
                                       + s * 32 + lq * 8);

        f32x4 accO[8];
        float m_i[4], l_i[4];
#pragma unroll
        for (int j = 0; j < 8; ++j) accO[j] = (f32x4){0.f, 0.f, 0.f, 0.f};
#pragma unroll
        for (int r = 0; r < 4; ++r) { m_i[r] = -1e30f; l_i[r] = 0.f; }

        stageK(0);

        for (int t = 0; t < NT; ++t) {
            const bool more = (t + 1 < NT);
            if (more) stageK(t + 1);
            stageV(t);
            // wait K(t) ready (issued last iter / prologue)
            if (more) asm volatile("s_waitcnt vmcnt(4)" ::: "memory");
            else      asm volatile("s_waitcnt vmcnt(2)" ::: "memory");
            __builtin_amdgcn_s_barrier();
            __builtin_amdgcn_sched_barrier(0);

            const bf16* Kbb = Ks + (t & 1) * (64 * 128);
            const int j0 = t * 64;
            // wave handles rows q0+wave*16..+15; tile fully-masked -> skip
            const bool active = (j0 <= q0 + wave * 16 + 15);

            if (active) {
                // --- QK^T: counted-lgkm pipelined asm ds_reads
                f32x4 accS[4];
#pragma unroll
                for (int nt = 0; nt < 4; ++nt) accS[nt] = (f32x4){0.f, 0.f, 0.f, 0.f};
                short8 bk[2][4];
#pragma unroll
                for (int nt = 0; nt < 4; ++nt)
                    DS_READ_B128(bk[0][nt],
                                 Kbb + (nt * 16 + lr) * 128 + ((lq * 8) ^ swz));
#pragma unroll
                for (int s = 0; s < 4; ++s) {
                    if (s + 1 < 4) {
#pragma unroll
                        for (int nt = 0; nt < 4; ++nt)
                            DS_READ_B128(bk[(s + 1) & 1][nt],
                                         Kbb + (nt * 16 + lr) * 128
                                             + (((s + 1) * 32 + lq * 8) ^ swz));
                        asm volatile("s_waitcnt lgkmcnt(4)" ::: "memory");
                    } else {
                        asm volatile("s_waitcnt lgkmcnt(0)" ::: "memory");
                    }
                    __builtin_amdgcn_sched_barrier(0);
#pragma unroll
                    for (int nt = 0; nt < 4; ++nt)
                        accS[nt] = __builtin_amdgcn_mfma_f32_16x16x32_bf16(
                            qreg[s], bk[s & 1][nt], accS[nt], 0, 0, 0);
                }

                // --- online softmax (wave-private Ps rows, swizzled)
                const bool need_mask = (j0 + 63 > q0 + wave * 16);
#pragma unroll
                for (int r = 0; r < 4; ++r) {
                    const int row = q0 + wave * 16 + lq * 4 + r;
                    float sv[4];
#pragma unroll
                    for (int nt = 0; nt < 4; ++nt) {
                        float v = accS[nt][r] * sc;
                        if (need_mask && (j0 + nt * 16 + lr > row)) v = -1e30f;
                        sv[nt] = v;
                    }
                    float mx = fmaxf(fmaxf(sv[0], sv[1]), fmaxf(sv[2], sv[3]));
#pragma unroll
                    for (int msk = 8; msk; msk >>= 1) mx = fmaxf(mx, __shfl_xor(mx, msk, 16));
                    float mnew = fmaxf(m_i[r], mx);
                    float al   = __expf(m_i[r] - mnew);
                    float rs = 0.f;
#pragma unroll
                    for (int nt = 0; nt < 4; ++nt) {
                        sv[nt] = __expf(sv[nt] - mnew);
                        rs += sv[nt];
                    }
#pragma unroll
                    for (int msk = 8; msk; msk >>= 1) rs += __shfl_xor(rs, msk, 16);
                    l_i[r] = l_i[r] * al + rs;
                    m_i[r] = mnew;
#pragma unroll
                    for (int d8 = 0; d8 < 8; ++d8) accO[d8][r] *= al;
                    const int prow = wave * 16 + lq * 4 + r;
                    const int pswz = (prow & 7) << 3;
#pragma unroll
                    for (int nt = 0; nt < 4; ++nt)
                        Ps[prow * 64 + ((nt * 16 + lr) ^ pswz)] = __float2bfloat16(sv[nt]);
                }
                asm volatile("" ::: "memory");
            }

            // V(t) ready (all waves drain their own V issues, then barrier)
            if (more) asm volatile("s_waitcnt vmcnt(2)" ::: "memory");
            else      asm volatile("s_waitcnt vmcnt(0)" ::: "memory");
            __builtin_amdgcn_s_barrier();
            __builtin_amdgcn_sched_barrier(0);

            if (active) {
                // --- PV: 2 k-slices, double-issued asm reads
                short8 ap[2], bv[2][8];
                DS_READ_B128(ap[0], Ps + (wave * 16 + lr) * 64 + ((lq * 8) ^ swz));
#pragma unroll
                for (int d8 = 0; d8 < 8; ++d8)
                    DS_READ_B128(bv[0][d8],
                                 Vs + (d8 * 16 + lr) * 64 + ((lq * 8) ^ swz));
#pragma unroll
                for (int kv = 0; kv < 2; ++kv) {
                    if (kv == 0) {
                        DS_READ_B128(ap[1],
                                     Ps + (wave * 16 + lr) * 64 + ((32 + lq * 8) ^ swz));
#pragma unroll
                        for (int d8 = 0; d8 < 8; ++d8)
                            DS_READ_B128(bv[1][d8],
                                         Vs + (d8 * 16 + lr) * 64 + ((32 + lq * 8) ^ swz));
                        asm volatile("s_waitcnt lgkmcnt(9)" ::: "memory");
                    } else {
                        asm volatile("s_waitcnt lgkmcnt(0)" ::: "memory");
                    }
                    __builtin_amdgcn_sched_barrier(0);
#pragma unroll
                    for (int d8 = 0; d8 < 8; ++d8)
                        accO[d8] = __builtin_amdgcn_mfma_f32_16x16x32_bf16(
                            ap[kv], bv[kv][d8], accO[d8], 0, 0, 0);
                }
            }

            __builtin_amdgcn_s_barrier();    // all V/K reads done before restage
        }

#pragma unroll
        for (int r = 0; r < 4; ++r) {
            const int t = q0 + wave * 16 + lq * 4 + r;
            const float inv = 1.0f / l_i[r];
            float* dst = z + (size_t)(b * 1024 + t) * ND + n * DD + slot * DH;
#pragma unroll
            for (int d8 = 0; d8 < 8; ++d8)
                dst[d8 * 16 + lr] += accO[d8][r] * inv;
        }
    }
}

// ---------------------------------------------------------------------------
// fp32 -> bf16 elementwise (n4 = n/4)
// ---------------------------------------------------------------------------
__global__ __launch_bounds__(256) void cvt_bf16_kernel(const float* __restrict__ src,
                                                       bf16* __restrict__ dst,
                                                       int n4)
{
    int i = blockIdx.x * 256 + threadIdx.x;
    if (i < n4) {
        float4 v = ((const float4*)src)[i];
        bf16* d = dst + (size_t)i * 4;
        d[0] = __float2bfloat16(v.x);
        d[1] = __float2bfloat16(v.y);
        d[2] = __float2bfloat16(v.z);
        d[3] = __float2bfloat16(v.w);
    }
}

// Wqkv (12,128,384) fp32 -> Wt (12,384,128) bf16
__global__ __launch_bounds__(256) void cvt_wqkv_kernel(const float* __restrict__ W,
                                                       bf16* __restrict__ Wt)
{
    int o = blockIdx.x * 256 + threadIdx.x;
    if (o < 12 * 384 * 128) {
        int i = o / 49152, rem = o % 49152;
        int e = rem / 128, d = rem % 128;
        Wt[o] = __float2bfloat16(W[(size_t)i * 49152 + d * 384 + e]);
    }
}

// ---------------------------------------------------------------------------
// Attention-input LayerNorm -> bf16 head-major xh. grid = GQ*256 blocks.
// ---------------------------------------------------------------------------
__global__ __launch_bounds__(256) void ln_attn_kernel(const float* __restrict__ z,
                                                      bf16* __restrict__ xh,
                                                      const float* __restrict__ scale,
                                                      const float* __restrict__ bias,
                                                      const int* __restrict__ phase_p,
                                                      int bt0)
{
    const int ph   = phase_p[0] & 3;
    const int lane = threadIdx.x & 63;
    const int row  = blockIdx.x * 4 + (threadIdx.x >> 6);
    const int k    = row % 3;
    const int n    = (row / 3) & 3;
    const int btl  = row / 12;
    const int slot = (k == 0) ? 0 : (k == 1 ? 1 + (ph & 1) : 3 + (ph & 3));
    const int bt   = bt0 + btl;

    const float* src = z + (size_t)bt * ND + n * DD + slot * DH + lane * 2;
    float2 v = *(const float2*)src;
    float s = v.x + v.y;
    float q = v.x * v.x + v.y * v.y;
#pragma unroll
    for (int m = 32; m; m >>= 1) { s += __shfl_xor(s, m); q += __shfl_xor(q, m); }
    float mu  = s * (1.0f / 128.0f);
    float var = q * (1.0f / 128.0f) - mu * mu;
    float r   = rsqrtf(var + 1e-5f);

    float2 sc2 = *(const float2*)(scale + lane * 2);
    float2 bi2 = *(const float2*)(bias + lane * 2);
    const int bl = btl >> 10, t = btl & 1023;
    union { bf16 h[2]; unsigned int u; } pk;
    pk.h[0] = __float2bfloat16((v.x - mu) * r * sc2.x + bi2.x);
    pk.h[1] = __float2bfloat16((v.y - mu) * r * sc2.y + bi2.y);
    *(unsigned int*)(xh + (size_t)((bl * 12 + n * 3 + k) * 1024 + t) * DH + lane * 2) = pk.u;
}

// ---------------------------------------------------------------------------
// Row LayerNorm, bf16 output. W=896 (mixer input) / W=3584 (decoder input).
// ---------------------------------------------------------------------------
template<int W>
__global__ __launch_bounds__(256) void ln_row_bf16_kernel(const float* __restrict__ in,
                                                          bf16* __restrict__ outp,
                                                          const float* __restrict__ scale,
                                                          const float* __restrict__ bias)
{
    constexpr int NIT = (W + 255) / 256;
    const int row = blockIdx.x;
    const int tid = threadIdx.x;
    const float* rp = in + (size_t)row * W;

    float v[NIT];
    float s = 0.f, q = 0.f;
#pragma unroll
    for (int i = 0; i < NIT; ++i) {
        int idx = tid + i * 256;
        if (idx < W) { float t = rp[idx]; v[i] = t; s += t; q += t * t; }
        else v[i] = 0.f;
    }
#pragma unroll
    for (int m = 32; m; m >>= 1) { s += __shfl_xor(s, m); q += __shfl_xor(q, m); }
    __shared__ float ss[4], sq[4];
    if ((tid & 63) == 0) { ss[tid >> 6] = s; sq[tid >> 6] = q; }
    __syncthreads();
    s = ss[0] + ss[1] + ss[2] + ss[3];
    q = sq[0] + sq[1] + sq[2] + sq[3];
    float mu  = s * (1.0f / W);
    float var = q * (1.0f / W) - mu * mu;
    float r   = rsqrtf(var + 1e-5f);

    bf16* op = outp + (size_t)row * W;
#pragma unroll
    for (int i = 0; i < NIT; ++i) {
        int idx = tid + i * 256;
        if (idx < W)
            op[idx] = __float2bfloat16((v[i] - mu) * r * scale[idx] + bias[idx]);
    }
}

// ---------------------------------------------------------------------------
// Launcher. ws-aware (ws>=205 MB proven by R6's CH=8192 run passing):
//   attn: GQ=96 (102 MB in R) if ws>=230 MB else GQ=48 (51.5 MB).
//   mixer: CH=8192 (86.2 MB) if ws>=205 MB else 4096 (49.5 MB).
//   decoder: zb 58.7 MB + dec_down_pad 0.92 MB + t1 2.1 MB in R (fits 88 MB).
// ---------------------------------------------------------------------------
extern "C" void kernel_launch(void* const* d_in, const int* in_sizes, int n_in,
                              void* d_out, int out_size, void* d_ws, size_t ws_size,
                              hipStream_t stream)
{
    const float* x          = (const float*)d_in[0];
    const float* enc_base_w = (const float*)d_in[1];
    const float* enc_A_w    = (const float*)d_in[2];
    const float* enc_B      = (const float*)d_in[3];
    const float* enc_beta   = (const float*)d_in[4];
    const float* Wqkv       = (const float*)d_in[5];
    const float* ln_attn_s  = (const float*)d_in[6];
    const float* ln_attn_b  = (const float*)d_in[7];
    const float* ln_mix_s   = (const float*)d_in[8];
    const float* ln_mix_b   = (const float*)d_in[9];
    const float* w1         = (const float*)d_in[10];
    const float* b1         = (const float*)d_in[11];
    const float* w2         = (const float*)d_in[12];
    const float* b2         = (const float*)d_in[13];
    const float* dec_ln_s   = (const float*)d_in[14];
    const float* dec_ln_b   = (const float*)d_in[15];
    const float* dec_down   = (const float*)d_in[16];
    const float* dec_up     = (const float*)d_in[17];
    const int*   phase_p    = (const int*)d_in[18];
    float* out = (float*)d_out;

    float* ws = (float*)d_ws;
    float* z  = ws;                                  // 8192*3584 fp32 (persistent)
    float* R  = ws + (size_t)BT * ND;

    const int GQ = (ws_size >= 230000000UL) ? 96 : 48;
    const int CH = (ws_size >= 205000000UL) ? 8192 : 4096;

    // encoder phase
    bf16* xb   = (bf16*)R;                           // 8192*1024
    bf16* Wenc = xb + (size_t)BT * IO;               // 3584*1024
    // attention phase
    bf16* Wt   = (bf16*)R;                           // 12*384*128
    bf16* xh_b = Wt + 12 * 384 * 128;                // GQ*1024*128
    bf16* Qb   = xh_b + (size_t)GQ * 1024 * 128;     // GQ*1024*128
    bf16* Kb   = Qb + (size_t)GQ * 1024 * 128;       // GQ*1024*128
    bf16* Vtg  = Kb + (size_t)GQ * 1024 * 128;       // GQ*128*1024
    // mixer phase
    bf16* w1b  = (bf16*)R;                           // 3584*896
    bf16* w2b  = w1b + (size_t)HID * DD;             // 896*3584
    bf16* hm   = w2b + (size_t)DD * HID;             // CH*896
    bf16* gbuf = hm + (size_t)CH * DD;               // CH*3584
    // dec phase
    bf16*  zb  = (bf16*)R;                           // 8192*3584 bf16 (LN'd)
    bf16*  ddp = zb + (size_t)BT * ND;               // 128*3584 bf16 (padded W)
    float* t1  = (float*)(ddp + 128 * ND);           // 8192*64 fp32

    // --- Encoder: fold low-rank into W_enc, then one bf16 GEMM into z
    cvt_bf16_kernel<<<dim3(8192), 256, 0, stream>>>(x, xb, BT * IO / 4);
    pack_enc_kernel<<<dim3(16, 56), 256, 0, stream>>>(enc_base_w, enc_A_w, enc_B,
                                                      enc_beta, Wenc);
    gemm_bf16_256<256, 0><<<dim3(14, 32), 512, 0, stream>>>(xb, Wenc, z, nullptr,
                                                            ND, IO, nullptr);

    // --- Attention (bf16 MFMA), GQ heads per group
    cvt_wqkv_kernel<<<dim3(2304), 256, 0, stream>>>(Wqkv, Wt);
    const int ngroups = 96 / GQ;
    for (int g = 0; g < ngroups; ++g) {
        ln_attn_kernel<<<dim3(GQ * 256), 256, 0, stream>>>(z, xh_b, ln_attn_s,
                                                           ln_attn_b, phase_p,
                                                           g * (GQ / 12) * 1024);
        qkv_bf16_kernel<<<dim3(3, 8, GQ), 256, 0, stream>>>(xh_b, Wt, Qb, Kb, Vtg,
                                                            phase_p, g * GQ);
        flash_bf16_kernel<<<dim3(GQ * 5), 512, 0, stream>>>(Qb, Kb, Vtg, z,
                                                            phase_p, g * GQ, GQ);
    }

    // --- Mixer MLP on bf16 MFMA, chunks of CH rows (of 32768 x 896)
    cvt_bf16_kernel<<<dim3(3136), 256, 0, stream>>>(w1, w1b, HID * DD / 4);
    cvt_bf16_kernel<<<dim3(3136), 256, 0, stream>>>(w2, w2b, DD * HID / 4);
    for (int c = 0; c < 32768 / CH; ++c) {
        float* zc = z + (size_t)c * CH * DD;
        ln_row_bf16_kernel<896><<<dim3(CH), 256, 0, stream>>>(zc, hm,
                                                              ln_mix_s, ln_mix_b);
        gemm_bf16_256<256, 1><<<dim3(14, CH / 256), 512, 0, stream>>>(
            hm, w1b, nullptr, gbuf, HID, DD, b1);
        gemm_bf16_256<128, 2><<<dim3(7, CH / 256), 512, 0, stream>>>(
            gbuf, w2b, zc, nullptr, DD, HID, b2);
    }

    // --- Decoder: LN -> bf16, MFMA split-K down-projection (8 segments,
    // atomicAdd into zeroed t1), fp32 up-projection.
    ln_row_bf16_kernel<3584><<<dim3(8192), 256, 0, stream>>>(z, zb,
                                                             dec_ln_s, dec_ln_b);
    hipMemsetAsync(ddp + (size_t)64 * ND, 0, (size_t)64 * ND * sizeof(bf16),
                   stream);
    cvt_bf16_kernel<<<dim3(224), 256, 0, stream>>>(dec_down, ddp, 64 * ND / 4);
    hipMemsetAsync(t1, 0, (size_t)BT * RK * sizeof(float), stream);
    gemm_bf16_256<128, 3><<<dim3(1, 32, 8), 512, 0, stream>>>(zb, ddp, t1,
                                                              nullptr, RK, ND,
                                                              nullptr);
    gemm_kernel<128, 128, 16, 8, 8>
        <<<dim3(8, 64), 256, 0, stream>>>(t1, dec_up, out, IO, RK);
}

// Round 9
// 1157.481 us; speedup vs baseline: 1.0592x; 1.0229x over previous
//
#include <hip/hip_runtime.h>
#include <hip/hip_bf16.h>
#include <math.h>

// ---------------------------------------------------------------------------
// Morpher forward. All large GEMMs bf16 MFMA; encoder low-rank folded;
// flash attention Q-in-registers.
// R8: flash LDS XOR-swizzle. R9: gemm_bf16_256 deep pipeline (counted vmcnt).
// R10: inline-asm ds_read_b128 (compiler LDS-DMA alias tracking re-inserted
//      vmcnt(0) -> depth-0; asm reads are opaque).
// R11: flash dbuf + counted vmcnt + LPT queue. R12: flash BQ=128 8-wave.
// R13: launch_bounds (512,2) fixes VGPR=64 scratch spill.
// R14: decoder down-projection onto MFMA path. R15: lgkm-split clusters;
//      split-K decoder GEMM.
// R16: (a) gemm_bf16_256 ring 4->2 slots: 128KB LDS forced 1 block/CU --
//      all 8 waves convoyed on the same vmcnt+barrier (occupancy 18%,
//      ~600TF 2-phase ceiling). 64KB -> 2 blocks/CU, inter-block overlap
//      hides the stage wait (m114). vmcnt ladder 2L/L.
//      (b) flash: revert R15's static schedule (103us) to R14 LPT queue
//      (measured 96us) -- static grid left CUs 2x-loaded / idle.
// Shapes: B=8 T=1024 (BT=8192), N=4, K=3, S=7, DH=128, D=896, ND=3584,
// IO=1024, RANK=64, HIDDEN=3584.
// ---------------------------------------------------------------------------

#define BT   8192
#define DH   128
#define DD   896
#define ND   3584
#define IO   1024
#define RK   64
#define HID  3584

typedef __attribute__((ext_vector_type(8))) short short8;
typedef __attribute__((ext_vector_type(4))) float f32x4;
typedef __hip_bfloat16 bf16;

// inline-asm LDS read: opaque to SIInsertWaitcnts' LDS-DMA tracking.
#define DS_READ_B128(dst, p)                                                  \
    asm volatile("ds_read_b128 %0, %1"                                        \
                 : "=v"(dst)                                                  \
                 : "v"((const __attribute__((address_space(3))) bf16*)(p)))

// Fast gelu: exact-form 0.5x(1+erf(x/sqrt2)) with A&S 7.1.26 erf
__device__ __forceinline__ float gelu_f(float v)
{
    float u = v * 0.70710678118654752f;
    float a = fabsf(u);
    float t = __builtin_amdgcn_rcpf(1.0f + 0.3275911f * a);
    float p = t * (0.254829592f + t * (-0.284496736f + t * (1.421413741f +
              t * (-1.453152027f + t * 1.061405429f))));
    float er = 1.0f - p * __expf(-u * u);
    er = copysignf(er, u);
    return 0.5f * v * (1.0f + er);
}

// ---------------------------------------------------------------------------
// fp32 tiled GEMM (decoder up-projection only). C = A @ B^T, B (N x Kd) rm.
// ---------------------------------------------------------------------------
template<int BM, int BN, int BK, int TM, int TN>
__global__ __launch_bounds__(256) void gemm_kernel(const float* __restrict__ A,
                                                   const float* __restrict__ B,
                                                   float* __restrict__ C,
                                                   int N, int Kd)
{
    constexpr int THREADS = (BM / TM) * (BN / TN);
    constexpr int LDA = BM + 4;
    constexpr int LDB = BN + 4;
    __shared__ float As[BK][LDA];
    __shared__ float Bs[BK][LDB];

    const int tid = threadIdx.x;
    constexpr int NX = BN / TN;
    const int tx = tid % NX;
    const int ty = tid / NX;
    const int row0 = blockIdx.y * BM;
    const int col0 = blockIdx.x * BN;

    float acc[TM][TN];
#pragma unroll
    for (int i = 0; i < TM; ++i)
#pragma unroll
        for (int j = 0; j < TN; ++j) acc[i][j] = 0.f;

    for (int k0 = 0; k0 < Kd; k0 += BK) {
        constexpr int AF4 = BM * BK / 4;
        for (int f = tid; f < AF4; f += THREADS) {
            int r  = f / (BK / 4);
            int c4 = (f % (BK / 4)) * 4;
            float4 v = *(const float4*)(A + (size_t)(row0 + r) * Kd + k0 + c4);
            As[c4 + 0][r] = v.x; As[c4 + 1][r] = v.y;
            As[c4 + 2][r] = v.z; As[c4 + 3][r] = v.w;
        }
        constexpr int BF4 = BN * BK / 4;
        for (int f = tid; f < BF4; f += THREADS) {
            int r  = f / (BK / 4);
            int c4 = (f % (BK / 4)) * 4;
            float4 v = *(const float4*)(B + (size_t)(col0 + r) * Kd + k0 + c4);
            Bs[c4 + 0][r] = v.x; Bs[c4 + 1][r] = v.y;
            Bs[c4 + 2][r] = v.z; Bs[c4 + 3][r] = v.w;
        }
        __syncthreads();

#pragma unroll
        for (int kk = 0; kk < BK; ++kk) {
            float a[TM], b[TN];
#pragma unroll
            for (int i = 0; i < TM; i += 4)
                *(float4*)&a[i] = *(const float4*)&As[kk][ty * TM + i];
#pragma unroll
            for (int j = 0; j < TN; j += 4)
                *(float4*)&b[j] = *(const float4*)&Bs[kk][tx * TN + j];
#pragma unroll
            for (int i = 0; i < TM; ++i)
#pragma unroll
                for (int j = 0; j < TN; ++j)
                    acc[i][j] = fmaf(a[i], b[j], acc[i][j]);
        }
        __syncthreads();
    }

    const int crow = row0 + ty * TM;
    const int ccol = col0 + tx * TN;
#pragma unroll
    for (int i = 0; i < TM; ++i) {
        float* cp = C + (size_t)(crow + i) * N + ccol;
#pragma unroll
        for (int j = 0; j < TN; ++j) cp[j] = acc[i][j];
    }
}

// ---------------------------------------------------------------------------
// R9/R10/R15/R16: bf16 MFMA GEMM, 256xBN tile, 8 waves (512 thr), C = A@B^T.
// 2-slot K-half LDS ring (64KB for BN=256 -> 2 blocks/CU), depth-1 prefetch
// via global_load_lds w16, counted vmcnt (2L outstanding, wait L), inline-asm
// ds_read_b128 fragments, lgkm-split dual MFMA clusters, setprio,
// XCD-chunked block swizzle. Split-K via gridDim.z.
//  EPI 0: Cf = acc ; 1: Cb = bf16(gelu(acc+bias)) ; 2: Cf += acc+bias ;
//  EPI 3: atomicAdd(Cf, acc)   (split-K, C pre-zeroed)
// ---------------------------------------------------------------------------
template<int BN, int EPI>
__global__ __launch_bounds__(512, 2) void gemm_bf16_256(
    const bf16* __restrict__ A,
    const bf16* __restrict__ B,
    float* __restrict__ Cf,
    bf16* __restrict__ Cb,
    int N, int Kd,
    const float* __restrict__ bias)
{
    constexpr int NR    = BN / 64;        // n-frags per wave (4 or 2)
    constexpr int WTN   = 16 * NR;        // wave tile cols
    constexpr int ASLOT = 256 * 32;       // elements per A K-half slot
    constexpr int BSLOT = BN * 32;
    __shared__ bf16 As[2 * ASLOT];
    __shared__ bf16 Bs[2 * BSLOT];

    const int tid  = threadIdx.x;
    const int wave = tid >> 6;
    const int lane = tid & 63;
    const int wm = wave >> 2, wn = wave & 3;
    const int lr = lane & 15, lq = lane >> 4;

    // T1: XCD-chunked block swizzle (nwg % 8 == 0 at every call site)
    const int gx  = gridDim.x;
    int fid = blockIdx.y * gx + blockIdx.x;
    const int cpx = (gx * gridDim.y) >> 3;
    fid = (fid & 7) * cpx + (fid >> 3);
    const int row0 = (fid / gx) * 256;
    const int col0 = (fid % gx) * BN;

    // split-K (gridDim.z segments; z==1 -> whole K)
    const int klen = Kd / (int)gridDim.z;
    const int kbeg = blockIdx.z * klen;

    // staging per-lane constants (16 rows x 64 B per wave-issue)
    const int sr  = lane >> 2;                               // 0..15
    const int scs = (((lane & 3) ^ ((lane >> 3) & 3)) << 3); // swizzled src col
    const bf16* Ag = A + (size_t)(row0 + sr) * Kd + kbeg + scs;
    const bf16* Bg = B + (size_t)(col0 + sr) * Kd + kbeg + scs;

    // read-side per-lane swizzle (row&15 == lr on every read path)
    const int scox = (lq * 8) ^ (((lr >> 1) & 3) << 3);

    f32x4 acc[8][NR];
#pragma unroll
    for (int i = 0; i < 8; ++i)
#pragma unroll
        for (int j = 0; j < NR; ++j) acc[i][j] = (f32x4){0.f, 0.f, 0.f, 0.f};

    const int NH = klen >> 5;   // number of K-halves (>= 14 at all call sites)

    auto stage = [&](int h) {
        const int slot = h & 1;
#pragma unroll
        for (int i = 0; i < 2; ++i) {
            const int rg = (i * 8 + wave) * 16;
            __builtin_amdgcn_global_load_lds(
                (const __attribute__((address_space(1))) unsigned int*)
                    (Ag + (size_t)rg * Kd + h * 32),
                (__attribute__((address_space(3))) unsigned int*)
                    (As + slot * ASLOT + rg * 32),
                16, 0, 0);
        }
#pragma unroll
        for (int i = 0; i < BN / 128; ++i) {
            const int rg = (i * 8 + wave) * 16;
            __builtin_amdgcn_global_load_lds(
                (const __attribute__((address_space(1))) unsigned int*)
                    (Bg + (size_t)rg * Kd + h * 32),
                (__attribute__((address_space(3))) unsigned int*)
                    (Bs + slot * BSLOT + rg * 32),
                16, 0, 0);
        }
    };

    // prologue: 1 K-half in flight (depth-1; 2 blocks/CU supply the overlap)
    stage(0);

    for (int h = 0; h < NH; ++h) {
        const bool more = (h + 1 < NH);
        if (more) stage(h + 1);

        // outstanding: stage(h) + stage(h+1) = 2L; wait L -> stage(h) landed.
        if constexpr (BN == 256) {   // LPH = 4
            if (more) asm volatile("s_waitcnt vmcnt(4)" ::: "memory");
            else      asm volatile("s_waitcnt vmcnt(0)" ::: "memory");
        } else {                     // LPH = 3
            if (more) asm volatile("s_waitcnt vmcnt(3)" ::: "memory");
            else      asm volatile("s_waitcnt vmcnt(0)" ::: "memory");
        }
        __builtin_amdgcn_s_barrier();            // all waves' half-h data in LDS

        const bf16* Ab = As + (h & 1) * ASLOT;
        const bf16* Bb = Bs + (h & 1) * BSLOT;

        short8 bfr[NR], afr[8];
#pragma unroll
        for (int nt = 0; nt < NR; ++nt)
            DS_READ_B128(bfr[nt], Bb + (wn * WTN + nt * 16 + lr) * 32 + scox);
#pragma unroll
        for (int mt = 0; mt < 8; ++mt)
            DS_READ_B128(afr[mt], Ab + (wm * 128 + mt * 16 + lr) * 32 + scox);

        // R15: wait only bfr + afr0-3 (leave last 4 A-reads in flight)
        asm volatile("s_waitcnt lgkmcnt(4)" ::: "memory");
        __builtin_amdgcn_sched_barrier(0);       // rule #18: pin MFMAs below wait

        __builtin_amdgcn_s_setprio(1);
#pragma unroll
        for (int mt = 0; mt < 4; ++mt)
#pragma unroll
            for (int nt = 0; nt < NR; ++nt)
                acc[mt][nt] = __builtin_amdgcn_mfma_f32_16x16x32_bf16(
                    afr[mt], bfr[nt], acc[mt][nt], 0, 0, 0);
        __builtin_amdgcn_s_setprio(0);

        asm volatile("s_waitcnt lgkmcnt(0)" ::: "memory");
        __builtin_amdgcn_sched_barrier(0);

        __builtin_amdgcn_s_setprio(1);
#pragma unroll
        for (int mt = 4; mt < 8; ++mt)
#pragma unroll
            for (int nt = 0; nt < NR; ++nt)
                acc[mt][nt] = __builtin_amdgcn_mfma_f32_16x16x32_bf16(
                    afr[mt], bfr[nt], acc[mt][nt], 0, 0, 0);
        __builtin_amdgcn_s_setprio(0);

        __builtin_amdgcn_s_barrier();            // all reads of slot h&1 done
    }

#pragma unroll
    for (int mt = 0; mt < 8; ++mt) {
#pragma unroll
        for (int nt = 0; nt < NR; ++nt) {
            const int col = col0 + wn * WTN + nt * 16 + lr;
            const bool cok = (col < N);
            const float bcol = (EPI == 0 || EPI == 3 || !cok) ? 0.f : bias[col];
#pragma unroll
            for (int r = 0; r < 4; ++r) {
                const int row = row0 + wm * 128 + mt * 16 + lq * 4 + r;
                float v = acc[mt][nt][r] + bcol;
                if (EPI == 1) {
                    if (cok) Cb[(size_t)row * N + col] = __float2bfloat16(gelu_f(v));
                } else if (EPI == 2) {
                    if (cok) Cf[(size_t)row * N + col] += v;
                } else if (EPI == 3) {
                    if (cok) atomicAdd(Cf + (size_t)row * N + col, v);
                } else {
                    if (cok) Cf[(size_t)row * N + col] = v;
                }
            }
        }
    }
}

// ---------------------------------------------------------------------------
// Encoder weight fold: W_enc[e,k] = enc_base_w[e%896,k] + beta*(B^T A)[e,k]
// out bf16 (3584 x 1024). grid (16, 56).
// ---------------------------------------------------------------------------
__global__ __launch_bounds__(256) void pack_enc_kernel(const float* __restrict__ baseW,
                                                       const float* __restrict__ Aw,
                                                       const float* __restrict__ Bv,
                                                       const float* __restrict__ betap,
                                                       bf16* __restrict__ outp)
{
    __shared__ float Ps[64][68];
    __shared__ float Qs[64][68];
    const int tid = threadIdx.x;
    const int e0 = blockIdx.y * 64;
    const int k0 = blockIdx.x * 64;

    for (int f = tid; f < 1024; f += 256) {
        int r = f >> 4, c4 = (f & 15) << 2;
        *(float4*)&Ps[r][c4] = *(const float4*)(Bv + (size_t)r * ND + e0 + c4);
        *(float4*)&Qs[r][c4] = *(const float4*)(Aw + (size_t)r * IO + k0 + c4);
    }
    __syncthreads();

    const int tx = tid & 15, ty = tid >> 4;
    float acc[4][4];
#pragma unroll
    for (int i = 0; i < 4; ++i)
#pragma unroll
        for (int j = 0; j < 4; ++j) acc[i][j] = 0.f;

#pragma unroll 8
    for (int r = 0; r < 64; ++r) {
        float a[4], b[4];
        *(float4*)a = *(const float4*)&Ps[r][ty * 4];
        *(float4*)b = *(const float4*)&Qs[r][tx * 4];
#pragma unroll
        for (int i = 0; i < 4; ++i)
#pragma unroll
            for (int j = 0; j < 4; ++j) acc[i][j] = fmaf(a[i], b[j], acc[i][j]);
    }

    const float beta = betap[0];
#pragma unroll
    for (int i = 0; i < 4; ++i) {
        const int e = e0 + ty * 4 + i;
        const int d = e % DD;
#pragma unroll
        for (int j = 0; j < 4; ++j) {
            const int k = k0 + tx * 4 + j;
            float v = baseW[(size_t)d * IO + k] + beta * acc[i][j];
            outp[(size_t)e * IO + k] = __float2bfloat16(v);
        }
    }
}

// ---------------------------------------------------------------------------
// QKV bf16 MFMA -> separate Q (t,d), K (t,d), V^T (d,t). grid (3, 8, GQ)
// ---------------------------------------------------------------------------
__global__ __launch_bounds__(256) void qkv_bf16_kernel(
    const bf16* __restrict__ xh,
    const bf16* __restrict__ Wt,
    bf16* __restrict__ Qg,
    bf16* __restrict__ Kg,
    bf16* __restrict__ Vtg,
    const int* __restrict__ phase_p,
    int go)
{
    __shared__ bf16 As[128 * 64];
    __shared__ bf16 Bs[128 * 64];

    const int ph  = phase_p[0] & 3;
    const int zbl = blockIdx.z;
    const int hh  = (go + zbl) % 12;
    const int n   = hh / 3;
    const int k   = hh % 3;
    const int m   = (k == 0) ? n
                  : (k == 1) ? ((n + 2 * (ph & 1)) & 3)
                             : ((n + (ph & 3)) & 3);
    const bf16* A  = xh + (size_t)zbl * (1024 * 128);
    const bf16* Bw = Wt + (size_t)(k * 4 + m) * (384 * 128);

    const int tid  = threadIdx.x;
    const int wave = tid >> 6;
    const int lane = tid & 63;
    const int wm = wave >> 1, wn = wave & 1;
    const int row0 = blockIdx.y * 128;
    const int col0 = blockIdx.x * 128;
    const int lr = lane & 15;
    const int lq = lane >> 4;
    const int srow = lane >> 3;
    const int scol = (lane & 7) * 8;

    f32x4 acc[4][4];
#pragma unroll
    for (int i = 0; i < 4; ++i)
#pragma unroll
        for (int j = 0; j < 4; ++j) acc[i][j] = (f32x4){0.f, 0.f, 0.f, 0.f};

#pragma unroll
    for (int k0 = 0; k0 < 128; k0 += 64) {
#pragma unroll
        for (int j = 0; j < 4; ++j) {
            const int rg = wave * 32 + j * 8;
            __builtin_amdgcn_global_load_lds(
                (const __attribute__((address_space(1))) unsigned int*)
                    (A + (size_t)(row0 + rg + srow) * 128 + k0 + scol),
                (__attribute__((address_space(3))) unsigned int*)(As + rg * 64),
                16, 0, 0);
        }
#pragma unroll
        for (int j = 0; j < 4; ++j) {
            const int rg = wave * 32 + j * 8;
            __builtin_amdgcn_global_load_lds(
                (const __attribute__((address_space(1))) unsigned int*)
                    (Bw + (size_t)(col0 + rg + srow) * 128 + k0 + scol),
                (__attribute__((address_space(3))) unsigned int*)(Bs + rg * 64),
                16, 0, 0);
        }
        __syncthreads();

#pragma unroll
        for (int s = 0; s < 64; s += 32) {
            short8 af[4], bf[4];
#pragma unroll
            for (int mt = 0; mt < 4; ++mt)
                af[mt] = *(const short8*)&As[(wm * 64 + mt * 16 + lr) * 64 + s + lq * 8];
#pragma unroll
            for (int nt = 0; nt < 4; ++nt)
                bf[nt] = *(const short8*)&Bs[(wn * 64 + nt * 16 + lr) * 64 + s + lq * 8];
#pragma unroll
            for (int mt = 0; mt < 4; ++mt)
#pragma unroll
                for (int nt = 0; nt < 4; ++nt)
                    acc[mt][nt] = __builtin_amdgcn_mfma_f32_16x16x32_bf16(
                        af[mt], bf[nt], acc[mt][nt], 0, 0, 0);
        }
        __syncthreads();
    }

    if (col0 < 256) {
        bf16* C = (col0 == 0 ? Qg : Kg) + (size_t)zbl * (1024 * 128);
#pragma unroll
        for (int mt = 0; mt < 4; ++mt)
#pragma unroll
            for (int nt = 0; nt < 4; ++nt) {
                const int col = wn * 64 + nt * 16 + lr;   // local 0..127
#pragma unroll
                for (int r = 0; r < 4; ++r) {
                    const int row = row0 + wm * 64 + mt * 16 + lq * 4 + r;
                    C[(size_t)row * 128 + col] = __float2bfloat16(acc[mt][nt][r]);
                }
            }
    } else {
        bf16* Vt = Vtg + (size_t)zbl * (128 * 1024);
#pragma unroll
        for (int mt = 0; mt < 4; ++mt)
#pragma unroll
            for (int nt = 0; nt < 4; ++nt) {
                const int d = wn * 64 + nt * 16 + lr;
                const int rowb = row0 + wm * 64 + mt * 16 + lq * 4;
                union { bf16 h[4]; uint2 u; } pk;
#pragma unroll
                for (int r = 0; r < 4; ++r)
                    pk.h[r] = __float2bfloat16(acc[mt][nt][r]);
                *(uint2*)(Vt + (size_t)d * 1024 + rowb) = pk.u;
            }
    }
}

// ---------------------------------------------------------------------------
// R12/R13/R16 flash attention: BQ=128, 8 waves (512 thr), persistent blocks
// + LPT work queue (R14 config, measured 96us vs static 103us). K dbuf,
// V single-buffered, Ps 128x64; 64KB LDS -> 2 blocks/CU; counted vmcnt;
// inline-asm LDS reads; 3 raw barriers/tile; R8 XOR swizzle.
// ---------------------------------------------------------------------------
__global__ __launch_bounds__(512, 2) void flash_bf16_kernel(
    const bf16* __restrict__ Qg,
    const bf16* __restrict__ Kg,
    const bf16* __restrict__ Vtg,
    float* __restrict__ z,
    const int* __restrict__ phase_p,
    int go, int GQ, int* __restrict__ cnt)
{
    __shared__ bf16 Ks[2 * 64 * 128];
    __shared__ bf16 Vs[128 * 64];
    __shared__ bf16 Ps[128 * 64];
    __shared__ int sw;

    const int ph   = phase_p[0] & 3;
    const int tid  = threadIdx.x;
    const int wave = tid >> 6;               // 0..7
    const int lane = tid & 63;
    const int lr = lane & 15;
    const int lq = lane >> 4;
    const int sr4 = lane >> 4, sc4 = (lane & 15) * 8;
    const int sr8 = lane >> 3, sc8 = (lane & 7) * 8;
    const int swz = (lr & 7) << 3;           // read-side swizzle (row&7==lr&7)
    const float sc = 0.08838834764831845f;   // 1/sqrt(128)
    const int nitems = GQ * 8;

    for (;;) {
        __syncthreads();
        if (tid == 0) sw = atomicAdd(cnt, 1);
        __syncthreads();
        const int w = sw;
        if (w >= nitems) return;

        const int wq  = w / GQ;
        const int qy8 = 7 - wq;              // heavy q-tiles first (LPT)
        const int zbl = w - wq * GQ;
        const int zb  = go + zbl;
        const int b   = zb / 12;
        const int hh  = zb % 12;
        const int n   = hh / 3;
        const int ksl = hh % 3;
        const int slot = (ksl == 0) ? 0 : (ksl == 1 ? 1 + (ph & 1) : 3 + (ph & 3));
        const int q0  = qy8 * 128;
        const int NT  = qy8 * 2 + 2;

        const bf16* Qp = Qg  + (size_t)zbl * (1024 * 128);
        const bf16* Kp = Kg  + (size_t)zbl * (1024 * 128);
        const bf16* Vp = Vtg + (size_t)zbl * (128 * 1024);

        // K tile t -> Ks[t&1]: 2 DMA issues/wave (8 waves cover 64 rows)
        auto stageK = [&](int t) {
            const int j0 = t * 64;
            bf16* Kd = Ks + (t & 1) * (64 * 128);
#pragma unroll
            for (int j = 0; j < 2; ++j) {
                const int rg = wave * 8 + j * 4;
                const int krow = rg + sr4;
                const int kcol = sc4 ^ ((krow & 7) << 3);    // pre-swizzled src
                __builtin_amdgcn_global_load_lds(
                    (const __attribute__((address_space(1))) unsigned int*)
                        (Kp + (size_t)(j0 + krow) * 128 + kcol),
                    (__attribute__((address_space(3))) unsigned int*)(Kd + rg * 128),
                    16, 0, 0);
            }
        };
        // V tile t -> Vs (single buffer): 2 DMA issues/wave (128 rows)
        auto stageV = [&](int t) {
            const int j0 = t * 64;
#pragma unroll
            for (int j = 0; j < 2; ++j) {
                const int rg = wave * 16 + j * 8;
                const int vrow = rg + sr8;
                const int vcol = sc8 ^ ((vrow & 7) << 3);    // pre-swizzled src
                __builtin_amdgcn_global_load_lds(
                    (const __attribute__((address_space(1))) unsigned int*)
                        (Vp + (size_t)vrow * 1024 + j0 + vcol),
                    (__attribute__((address_space(3))) unsigned int*)(Vs + rg * 64),
                    16, 0, 0);
            }
        };

        short8 qreg[4];
#pragma unroll
        for (int s = 0; s < 4; ++s)
            qreg[s] = *(const short8*)(Qp + (size_t)(q0 + wave * 16 + lr) * 128
                                       + s * 32 + lq * 8);

        f32x4 accO[8];
        float m_i[4], l_i[4];
#pragma unroll
        for (int j = 0; j < 8; ++j) accO[j] = (f32x4){0.f, 0.f, 0.f, 0.f};
#pragma unroll
        for (int r = 0; r < 4; ++r) { m_i[r] = -1e30f; l_i[r] = 0.f; }

        stageK(0);

        for (int t = 0; t < NT; ++t) {
            const bool more = (t + 1 < NT);
            if (more) stageK(t + 1);
            stageV(t);
            // wait K(t) ready (issued last iter / prologue)
            if (more) asm volatile("s_waitcnt vmcnt(4)" ::: "memory");
            else      asm volatile("s_waitcnt vmcnt(2)" ::: "memory");
            __builtin_amdgcn_s_barrier();
            __builtin_amdgcn_sched_barrier(0);

            const bf16* Kbb = Ks + (t & 1) * (64 * 128);
            const int j0 = t * 64;
            // wave handles rows q0+wave*16..+15; tile fully-masked -> skip
            const bool active = (j0 <= q0 + wave * 16 + 15);

            if (active) {
                // --- QK^T: counted-lgkm pipelined asm ds_reads
                f32x4 accS[4];
#pragma unroll
                for (int nt = 0; nt < 4; ++nt) accS[nt] = (f32x4){0.f, 0.f, 0.f, 0.f};
                short8 bk[2][4];
#pragma unroll
                for (int nt = 0; nt < 4; ++nt)
                    DS_READ_B128(bk[0][nt],
                                 Kbb + (nt * 16 + lr) * 128 + ((lq * 8) ^ swz));
#pragma unroll
                for (int s = 0; s < 4; ++s) {
                    if (s + 1 < 4) {
#pragma unroll
                        for (int nt = 0; nt < 4; ++nt)
                            DS_READ_B128(bk[(s + 1) & 1][nt],
                                         Kbb + (nt * 16 + lr) * 128
                                             + (((s + 1) * 32 + lq * 8) ^ swz));
                        asm volatile("s_waitcnt lgkmcnt(4)" ::: "memory");
                    } else {
                        asm volatile("s_waitcnt lgkmcnt(0)" ::: "memory");
                    }
                    __builtin_amdgcn_sched_barrier(0);
#pragma unroll
                    for (int nt = 0; nt < 4; ++nt)
                        accS[nt] = __builtin_amdgcn_mfma_f32_16x16x32_bf16(
                            qreg[s], bk[s & 1][nt], accS[nt], 0, 0, 0);
                }

                // --- online softmax (wave-private Ps rows, swizzled)
                const bool need_mask = (j0 + 63 > q0 + wave * 16);
#pragma unroll
                for (int r = 0; r < 4; ++r) {
                    const int row = q0 + wave * 16 + lq * 4 + r;
                    float sv[4];
#pragma unroll
                    for (int nt = 0; nt < 4; ++nt) {
                        float v = accS[nt][r] * sc;
                        if (need_mask && (j0 + nt * 16 + lr > row)) v = -1e30f;
                        sv[nt] = v;
                    }
                    float mx = fmaxf(fmaxf(sv[0], sv[1]), fmaxf(sv[2], sv[3]));
#pragma unroll
                    for (int msk = 8; msk; msk >>= 1) mx = fmaxf(mx, __shfl_xor(mx, msk, 16));
                    float mnew = fmaxf(m_i[r], mx);
                    float al   = __expf(m_i[r] - mnew);
                    float rs = 0.f;
#pragma unroll
                    for (int nt = 0; nt < 4; ++nt) {
                        sv[nt] = __expf(sv[nt] - mnew);
                        rs += sv[nt];
                    }
#pragma unroll
                    for (int msk = 8; msk; msk >>= 1) rs += __shfl_xor(rs, msk, 16);
                    l_i[r] = l_i[r] * al + rs;
                    m_i[r] = mnew;
#pragma unroll
                    for (int d8 = 0; d8 < 8; ++d8) accO[d8][r] *= al;
                    const int prow = wave * 16 + lq * 4 + r;
                    const int pswz = (prow & 7) << 3;
#pragma unroll
                    for (int nt = 0; nt < 4; ++nt)
                        Ps[prow * 64 + ((nt * 16 + lr) ^ pswz)] = __float2bfloat16(sv[nt]);
                }
                asm volatile("" ::: "memory");
            }

            // V(t) ready (all waves drain their own V issues, then barrier)
            if (more) asm volatile("s_waitcnt vmcnt(2)" ::: "memory");
            else      asm volatile("s_waitcnt vmcnt(0)" ::: "memory");
            __builtin_amdgcn_s_barrier();
            __builtin_amdgcn_sched_barrier(0);

            if (active) {
                // --- PV: 2 k-slices, double-issued asm reads
                short8 ap[2], bv[2][8];
                DS_READ_B128(ap[0], Ps + (wave * 16 + lr) * 64 + ((lq * 8) ^ swz));
#pragma unroll
                for (int d8 = 0; d8 < 8; ++d8)
                    DS_READ_B128(bv[0][d8],
                                 Vs + (d8 * 16 + lr) * 64 + ((lq * 8) ^ swz));
#pragma unroll
                for (int kv = 0; kv < 2; ++kv) {
                    if (kv == 0) {
                        DS_READ_B128(ap[1],
                                     Ps + (wave * 16 + lr) * 64 + ((32 + lq * 8) ^ swz));
#pragma unroll
                        for (int d8 = 0; d8 < 8; ++d8)
                            DS_READ_B128(bv[1][d8],
                                         Vs + (d8 * 16 + lr) * 64 + ((32 + lq * 8) ^ swz));
                        asm volatile("s_waitcnt lgkmcnt(9)" ::: "memory");
                    } else {
                        asm volatile("s_waitcnt lgkmcnt(0)" ::: "memory");
                    }
                    __builtin_amdgcn_sched_barrier(0);
#pragma unroll
                    for (int d8 = 0; d8 < 8; ++d8)
                        accO[d8] = __builtin_amdgcn_mfma_f32_16x16x32_bf16(
                            ap[kv], bv[kv][d8], accO[d8], 0, 0, 0);
                }
            }

            __builtin_amdgcn_s_barrier();    // all V/K reads done before restage
        }

#pragma unroll
        for (int r = 0; r < 4; ++r) {
            const int t = q0 + wave * 16 + lq * 4 + r;
            const float inv = 1.0f / l_i[r];
            float* dst = z + (size_t)(b * 1024 + t) * ND + n * DD + slot * DH;
#pragma unroll
            for (int d8 = 0; d8 < 8; ++d8)
                dst[d8 * 16 + lr] += accO[d8][r] * inv;
        }
    }
}

// ---------------------------------------------------------------------------
// fp32 -> bf16 elementwise (n4 = n/4)
// ---------------------------------------------------------------------------
__global__ __launch_bounds__(256) void cvt_bf16_kernel(const float* __restrict__ src,
                                                       bf16* __restrict__ dst,
                                                       int n4)
{
    int i = blockIdx.x * 256 + threadIdx.x;
    if (i < n4) {
        float4 v = ((const float4*)src)[i];
        bf16* d = dst + (size_t)i * 4;
        d[0] = __float2bfloat16(v.x);
        d[1] = __float2bfloat16(v.y);
        d[2] = __float2bfloat16(v.z);
        d[3] = __float2bfloat16(v.w);
    }
}

// Wqkv (12,128,384) fp32 -> Wt (12,384,128) bf16
__global__ __launch_bounds__(256) void cvt_wqkv_kernel(const float* __restrict__ W,
                                                       bf16* __restrict__ Wt)
{
    int o = blockIdx.x * 256 + threadIdx.x;
    if (o < 12 * 384 * 128) {
        int i = o / 49152, rem = o % 49152;
        int e = rem / 128, d = rem % 128;
        Wt[o] = __float2bfloat16(W[(size_t)i * 49152 + d * 384 + e]);
    }
}

// ---------------------------------------------------------------------------
// Attention-input LayerNorm -> bf16 head-major xh. grid = GQ*256 blocks.
// ---------------------------------------------------------------------------
__global__ __launch_bounds__(256) void ln_attn_kernel(const float* __restrict__ z,
                                                      bf16* __restrict__ xh,
                                                      const float* __restrict__ scale,
                                                      const float* __restrict__ bias,
                                                      const int* __restrict__ phase_p,
                                                      int bt0)
{
    const int ph   = phase_p[0] & 3;
    const int lane = threadIdx.x & 63;
    const int row  = blockIdx.x * 4 + (threadIdx.x >> 6);
    const int k    = row % 3;
    const int n    = (row / 3) & 3;
    const int btl  = row / 12;
    const int slot = (k == 0) ? 0 : (k == 1 ? 1 + (ph & 1) : 3 + (ph & 3));
    const int bt   = bt0 + btl;

    const float* src = z + (size_t)bt * ND + n * DD + slot * DH + lane * 2;
    float2 v = *(const float2*)src;
    float s = v.x + v.y;
    float q = v.x * v.x + v.y * v.y;
#pragma unroll
    for (int m = 32; m; m >>= 1) { s += __shfl_xor(s, m); q += __shfl_xor(q, m); }
    float mu  = s * (1.0f / 128.0f);
    float var = q * (1.0f / 128.0f) - mu * mu;
    float r   = rsqrtf(var + 1e-5f);

    float2 sc2 = *(const float2*)(scale + lane * 2);
    float2 bi2 = *(const float2*)(bias + lane * 2);
    const int bl = btl >> 10, t = btl & 1023;
    union { bf16 h[2]; unsigned int u; } pk;
    pk.h[0] = __float2bfloat16((v.x - mu) * r * sc2.x + bi2.x);
    pk.h[1] = __float2bfloat16((v.y - mu) * r * sc2.y + bi2.y);
    *(unsigned int*)(xh + (size_t)((bl * 12 + n * 3 + k) * 1024 + t) * DH + lane * 2) = pk.u;
}

// ---------------------------------------------------------------------------
// Row LayerNorm, bf16 output. W=896 (mixer input) / W=3584 (decoder input).
// ---------------------------------------------------------------------------
template<int W>
__global__ __launch_bounds__(256) void ln_row_bf16_kernel(const float* __restrict__ in,
                                                          bf16* __restrict__ outp,
                                                          const float* __restrict__ scale,
                                                          const float* __restrict__ bias)
{
    constexpr int NIT = (W + 255) / 256;
    const int row = blockIdx.x;
    const int tid = threadIdx.x;
    const float* rp = in + (size_t)row * W;

    float v[NIT];
    float s = 0.f, q = 0.f;
#pragma unroll
    for (int i = 0; i < NIT; ++i) {
        int idx = tid + i * 256;
        if (idx < W) { float t = rp[idx]; v[i] = t; s += t; q += t * t; }
        else v[i] = 0.f;
    }
#pragma unroll
    for (int m = 32; m; m >>= 1) { s += __shfl_xor(s, m); q += __shfl_xor(q, m); }
    __shared__ float ss[4], sq[4];
    if ((tid & 63) == 0) { ss[tid >> 6] = s; sq[tid >> 6] = q; }
    __syncthreads();
    s = ss[0] + ss[1] + ss[2] + ss[3];
    q = sq[0] + sq[1] + sq[2] + sq[3];
    float mu  = s * (1.0f / W);
    float var = q * (1.0f / W) - mu * mu;
    float r   = rsqrtf(var + 1e-5f);

    bf16* op = outp + (size_t)row * W;
#pragma unroll
    for (int i = 0; i < NIT; ++i) {
        int idx = tid + i * 256;
        if (idx < W)
            op[idx] = __float2bfloat16((v[i] - mu) * r * scale[idx] + bias[idx]);
    }
}

// ---------------------------------------------------------------------------
// Launcher. ws-aware (ws>=205 MB proven by R6's CH=8192 run passing):
//   attn: GQ=96 (102 MB in R) if ws>=230 MB else GQ=48 (51.5 MB).
//   mixer: CH=8192 (86.2 MB) if ws>=205 MB else 4096 (49.5 MB).
//   decoder: zb 58.7 MB + dec_down_pad 0.92 MB + t1 2.1 MB in R (fits 88 MB).
// ---------------------------------------------------------------------------
extern "C" void kernel_launch(void* const* d_in, const int* in_sizes, int n_in,
                              void* d_out, int out_size, void* d_ws, size_t ws_size,
                              hipStream_t stream)
{
    const float* x          = (const float*)d_in[0];
    const float* enc_base_w = (const float*)d_in[1];
    const float* enc_A_w    = (const float*)d_in[2];
    const float* enc_B      = (const float*)d_in[3];
    const float* enc_beta   = (const float*)d_in[4];
    const float* Wqkv       = (const float*)d_in[5];
    const float* ln_attn_s  = (const float*)d_in[6];
    const float* ln_attn_b  = (const float*)d_in[7];
    const float* ln_mix_s   = (const float*)d_in[8];
    const float* ln_mix_b   = (const float*)d_in[9];
    const float* w1         = (const float*)d_in[10];
    const float* b1         = (const float*)d_in[11];
    const float* w2         = (const float*)d_in[12];
    const float* b2         = (const float*)d_in[13];
    const float* dec_ln_s   = (const float*)d_in[14];
    const float* dec_ln_b   = (const float*)d_in[15];
    const float* dec_down   = (const float*)d_in[16];
    const float* dec_up     = (const float*)d_in[17];
    const int*   phase_p    = (const int*)d_in[18];
    float* out = (float*)d_out;

    float* ws = (float*)d_ws;
    float* z  = ws;                                  // 8192*3584 fp32 (persistent)
    float* R  = ws + (size_t)BT * ND;

    const int GQ = (ws_size >= 230000000UL) ? 96 : 48;
    const int CH = (ws_size >= 205000000UL) ? 8192 : 4096;

    // encoder phase
    bf16* xb   = (bf16*)R;                           // 8192*1024
    bf16* Wenc = xb + (size_t)BT * IO;               // 3584*1024
    // attention phase
    bf16* Wt   = (bf16*)R;                           // 12*384*128
    bf16* xh_b = Wt + 12 * 384 * 128;                // GQ*1024*128
    bf16* Qb   = xh_b + (size_t)GQ * 1024 * 128;     // GQ*1024*128
    bf16* Kb   = Qb + (size_t)GQ * 1024 * 128;       // GQ*1024*128
    bf16* Vtg  = Kb + (size_t)GQ * 1024 * 128;       // GQ*128*1024
    int*  cnt  = (int*)(Vtg + (size_t)GQ * 128 * 1024);  // 2 ints (work queue)
    // mixer phase
    bf16* w1b  = (bf16*)R;                           // 3584*896
    bf16* w2b  = w1b + (size_t)HID * DD;             // 896*3584
    bf16* hm   = w2b + (size_t)DD * HID;             // CH*896
    bf16* gbuf = hm + (size_t)CH * DD;               // CH*3584
    // dec phase
    bf16*  zb  = (bf16*)R;                           // 8192*3584 bf16 (LN'd)
    bf16*  ddp = zb + (size_t)BT * ND;               // 128*3584 bf16 (padded W)
    float* t1  = (float*)(ddp + 128 * ND);           // 8192*64 fp32

    // --- Encoder: fold low-rank into W_enc, then one bf16 GEMM into z
    cvt_bf16_kernel<<<dim3(8192), 256, 0, stream>>>(x, xb, BT * IO / 4);
    pack_enc_kernel<<<dim3(16, 56), 256, 0, stream>>>(enc_base_w, enc_A_w, enc_B,
                                                      enc_beta, Wenc);
    gemm_bf16_256<256, 0><<<dim3(14, 32), 512, 0, stream>>>(xb, Wenc, z, nullptr,
                                                            ND, IO, nullptr);

    // --- Attention (bf16 MFMA), GQ heads per group
    cvt_wqkv_kernel<<<dim3(2304), 256, 0, stream>>>(Wqkv, Wt);
    hipMemsetAsync(cnt, 0, 2 * sizeof(int), stream);
    const int ngroups = 96 / GQ;
    for (int g = 0; g < ngroups; ++g) {
        ln_attn_kernel<<<dim3(GQ * 256), 256, 0, stream>>>(z, xh_b, ln_attn_s,
                                                           ln_attn_b, phase_p,
                                                           g * (GQ / 12) * 1024);
        qkv_bf16_kernel<<<dim3(3, 8, GQ), 256, 0, stream>>>(xh_b, Wt, Qb, Kb, Vtg,
                                                            phase_p, g * GQ);
        flash_bf16_kernel<<<dim3(512), 512, 0, stream>>>(Qb, Kb, Vtg, z,
                                                         phase_p, g * GQ, GQ,
                                                         cnt + g);
    }

    // --- Mixer MLP on bf16 MFMA, chunks of CH rows (of 32768 x 896)
    cvt_bf16_kernel<<<dim3(3136), 256, 0, stream>>>(w1, w1b, HID * DD / 4);
    cvt_bf16_kernel<<<dim3(3136), 256, 0, stream>>>(w2, w2b, DD * HID / 4);
    for (int c = 0; c < 32768 / CH; ++c) {
        float* zc = z + (size_t)c * CH * DD;
        ln_row_bf16_kernel<896><<<dim3(CH), 256, 0, stream>>>(zc, hm,
                                                              ln_mix_s, ln_mix_b);
        gemm_bf16_256<256, 1><<<dim3(14, CH / 256), 512, 0, stream>>>(
            hm, w1b, nullptr, gbuf, HID, DD, b1);
        gemm_bf16_256<128, 2><<<dim3(7, CH / 256), 512, 0, stream>>>(
            gbuf, w2b, zc, nullptr, DD, HID, b2);
    }

    // --- Decoder: LN -> bf16, MFMA split-K down-projection (8 segments,
    // atomicAdd into zeroed t1), fp32 up-projection.
    ln_row_bf16_kernel<3584><<<dim3(8192), 256, 0, stream>>>(z, zb,
                                                             dec_ln_s, dec_ln_b);
    hipMemsetAsync(ddp + (size_t)64 * ND, 0, (size_t)64 * ND * sizeof(bf16),
                   stream);
    cvt_bf16_kernel<<<dim3(224), 256, 0, stream>>>(dec_down, ddp, 64 * ND / 4);
    hipMemsetAsync(t1, 0, (size_t)BT * RK * sizeof(float), stream);
    gemm_bf16_256<128, 3><<<dim3(1, 32, 8), 512, 0, stream>>>(zb, ddp, t1,
                                                              nullptr, RK, ND,
                                                              nullptr);
    gemm_kernel<128, 128, 16, 8, 8>
        <<<dim3(8, 64), 256, 0, stream>>>(t1, dec_up, out, IO, RK);
}